// Round 14
// baseline (720.683 us; speedup 1.0000x reference)
//
#include <hip/hip_runtime.h>
#include <hip/hip_bf16.h>

typedef float f32x4 __attribute__((ext_vector_type(4)));
typedef short s16x8 __attribute__((ext_vector_type(8)));

__device__ __forceinline__ float pv_sigm(float x){ return 1.0f/(1.0f + __expf(-x)); }
__device__ __forceinline__ float pv_tanh(float x){ float e = __expf(2.0f*x); return 1.0f - 2.0f/(e + 1.0f); }

__device__ __forceinline__ unsigned short pv_f2b(float x){
  union { float f; unsigned u; } c; c.f = x;
  unsigned r = (c.u + 0x7fffu + ((c.u >> 16) & 1u)) >> 16;
  return (unsigned short)r;
}
__device__ __forceinline__ unsigned pv_pack2(float a, float b){
  return ((unsigned)pv_f2b(b) << 16) | (unsigned)pv_f2b(a);
}
__device__ __forceinline__ float pv_lo(unsigned u){
  union { unsigned u; float f; } c; c.u = u << 16; return c.f;
}
__device__ __forceinline__ float pv_hi(unsigned u){
  union { unsigned u; float f; } c; c.u = u & 0xffff0000u; return c.f;
}

// manual OCP e4m3fn encode (RNE); valid for |x| < 448
__device__ __forceinline__ unsigned char pv_fp8(float x){
  union { float f; unsigned u; } c; c.f = x;
  unsigned s = (c.u >> 24) & 0x80u;
  unsigned au = c.u & 0x7fffffffu;
  if (au == 0u) return (unsigned char)s;
  int ex = (int)(au >> 23) - 127;
  if (ex < -6) ex = -6;
  union { unsigned u; float f; } iv; iv.u = (unsigned)(3 - ex + 127) << 23;
  union { unsigned u; float f; } a;  a.u = au;
  int q = (int)rintf(a.f * iv.f);
  if (q >= 16) { q >>= 1; ex += 1; }
  unsigned bits;
  if (ex == -6 && q < 8) bits = (unsigned)q;
  else bits = (unsigned)(((ex + 7) << 3) | (q - 8));
  return (unsigned char)(s | bits);
}

#if defined(__has_builtin)
#if __has_builtin(__builtin_amdgcn_cvt_pk_fp8_f32)
#define PV_HW_FP8 1
#endif
#endif
__device__ __forceinline__ unsigned char pv_fp8_fast(float x){
#ifdef PV_HW_FP8
  return (unsigned char)__builtin_amdgcn_cvt_pk_fp8_f32(x, x, 0, false);
#else
  return pv_fp8(x);
#endif
}

// ---------------------------------------------------------------------------
// pv_prep_gru8: unchanged (verified r4-r13).
// ---------------------------------------------------------------------------
__global__ void pv_prep_gru8(const float* Whh, const float* Wih,
                             unsigned long long* wfp8){
  int idx = blockIdx.x*256 + threadIdx.x;   // < 51*9*64 = 29376
  if (idx >= 29376) return;
  int T = idx / 576;
  int rem = idx - T*576;
  int c = rem >> 6;
  int l = rem & 63;
  int l16 = l & 15;
  int quad = l >> 4;
  int jb = T / 3;
  int ty = T - jb*3;
  int j = jb*16 + l16;
  int g = ty*261 + j;
  unsigned long long v = 0ull;
  #pragma unroll
  for (int e = 0; e < 8; ++e) {
    int k = c*32 + quad*8 + e;
    float w = 0.0f;
    if (j < 261) {
      if (k < 261) w = Whh[g*261 + k];
      else if (k < 266 && ty < 2) w = Wih[g*261 + 256 + (k - 261)];
    }
    v |= (unsigned long long)pv_fp8(8.0f*w) << (8*e);
  }
  wfp8[idx] = v;
}

// ---------------------------------------------------------------------------
// pv_prep_wih: unchanged.
// ---------------------------------------------------------------------------
__global__ __launch_bounds__(256) void pv_prep_wih(
    const float* __restrict__ Wih, unsigned* __restrict__ wihb)
{
  const int idx = blockIdx.x*256 + threadIdx.x;      // 262144 threads
  if (idx >= 262144) return;
  const float* src = Wih + idx*8;
  float4 a = *(const float4*)(src);
  float4 b = *(const float4*)(src + 4);
  uint4 o;
  o.x = pv_pack2(a.x, a.y);
  o.y = pv_pack2(a.z, a.w);
  o.z = pv_pack2(b.x, b.y);
  o.w = pv_pack2(b.z, b.w);
  *(uint4*)(wihb + idx*4) = o;
}

// ---------------------------------------------------------------------------
// pv_gemm4k: r13 change = 4-WAY K-SPLIT of the verified gemm4.  gemm4 ran
// 200 blocks (1/CU) x 128 serial K-steps: every barrier/vmcnt stall fully
// exposed, nothing co-resident.  Now blockIdx.z in 0..3 owns K-steps
// [32z, 32z+32): 800 blocks => 2 blocks/CU co-resident (LDS 54KB), serial
// chain per block quartered; stalls of one block hide under the other's
// compute.  Each z writes an f32 PARTIAL (no bias); pv_xgadd sums the 4
// partials + bias.  Per-partial accumulation order identical to gemm4.
// ---------------------------------------------------------------------------
__global__ __launch_bounds__(512, 1) void pv_gemm4k(
    const float* __restrict__ pose, const float* __restrict__ projW,
    const float* __restrict__ projb, const unsigned* __restrict__ wihb,
    float* __restrict__ xg, float* __restrict__ xgp)
{
  __shared__ __align__(16) unsigned As2[128*20];      // A bf16 [128][40s]
  __shared__ __align__(16) unsigned Bs2[2][256*20];   // B bf16 [256][40s], dbuf
  __shared__ __align__(16) float Ws2[2][320];         // W^T: [j*32+kl], bias 288+

  const int tid = threadIdx.x;
  const int m0 = blockIdx.x * 128;
  const int n0 = blockIdx.y * 256;
  const int zz = blockIdx.z;
  const int k0 = zz * 32;
  float* outp = (zz == 0) ? xg : xgp + (size_t)(zz - 1)*6553600u;

  const int wave = tid >> 6, lane = tid & 63;
  const int wm = wave >> 2, wn = wave & 3;
  const int l16 = lane & 15, quad = lane >> 4;
  const int rl = tid >> 2, kq = tid & 3;       // A-gen: row rl, k-quarter kq
  const int rb = tid >> 1, hb = tid & 1;       // B-stage: row rb, half hb

  float p[9];
  {
    const float* pr = pose + (m0 + rl)*9;
    #pragma unroll
    for (int j = 0; j < 9; ++j) p[j] = pr[j];
  }

  if (tid < 320) {
    Ws2[0][tid < 288 ? ((tid >> 5)*32 + (tid & 31)) : tid] =
        (tid < 288) ? projW[k0*288 + (tid & 31)*9 + (tid >> 5)]
                    : projb[k0*32 + (tid - 288)];
  }
  {
    const unsigned* src = wihb + (n0 + rb)*2048 + k0*16 + hb*8;
    *(uint4*)(&Bs2[0][rb*20 + hb*8])     = *(const uint4*)(src);
    *(uint4*)(&Bs2[0][rb*20 + hb*8 + 4]) = *(const uint4*)(src + 4);
  }
  __syncthreads();

  f32x4 acc[4][4];
  #pragma unroll
  for (int i = 0; i < 4; ++i)
    #pragma unroll
    for (int j = 0; j < 4; ++j) acc[i][j] = (f32x4){0.f,0.f,0.f,0.f};

  for (int kk = k0; kk < k0 + 32; ++kk) {
    const int cur = kk & 1, nxt = cur ^ 1;
    const int kn = kk + 1;
    const int more = (kn < k0 + 32);

    // phase 1: issue loads for kk+1 (in flight through MFMA phase)
    uint4 bn0, bn1; float wv = 0.0f;
    if (more) {
      const unsigned* bsrc = wihb + (n0 + rb)*2048 + kn*16 + hb*8;
      bn0 = *(const uint4*)(bsrc);
      bn1 = *(const uint4*)(bsrc + 4);
      if (tid < 320)
        wv = (tid < 288) ? projW[kn*288 + (tid & 31)*9 + (tid >> 5)]
                         : projb[kn*32 + (tid - 288)];
    }

    // phase 2: A-gen for kk (bit-identical math)
    {
      const float* W = Ws2[cur];
      f32x4 slo = *(const f32x4*)(W + 288 + kq*8);
      f32x4 shi = *(const f32x4*)(W + 292 + kq*8);
      #pragma unroll
      for (int j = 0; j < 9; ++j) {
        f32x4 wlo = *(const f32x4*)(W + j*32 + kq*8);
        f32x4 whi = *(const f32x4*)(W + j*32 + kq*8 + 4);
        slo += p[j]*wlo;
        shi += p[j]*whi;
      }
      #pragma unroll
      for (int e = 0; e < 4; ++e) {
        slo[e] = fmaxf(slo[e], 0.1f*slo[e]);
        shi[e] = fmaxf(shi[e], 0.1f*shi[e]);
      }
      uint4 av;
      av.x = pv_pack2(slo[0], slo[1]);
      av.y = pv_pack2(slo[2], slo[3]);
      av.z = pv_pack2(shi[0], shi[1]);
      av.w = pv_pack2(shi[2], shi[3]);
      *(uint4*)(&As2[rl*20 + kq*4]) = av;
    }
    __syncthreads();   // barrier 1: As2 ready

    // phase 3: MFMA for kk
    {
      const unsigned short* As16 = (const unsigned short*)As2;
      const unsigned short* Bs16 = (const unsigned short*)Bs2[cur];
      s16x8 af[4];
      #pragma unroll
      for (int i = 0; i < 4; ++i)
        af[i] = *(const s16x8*)(As16 + (wm*64 + i*16 + l16)*40 + quad*8);
      #pragma unroll
      for (int j = 0; j < 4; ++j) {
        s16x8 bv = *(const s16x8*)(Bs16 + (wn*64 + j*16 + l16)*40 + quad*8);
        #pragma unroll
        for (int i = 0; i < 4; ++i)
          acc[i][j] = __builtin_amdgcn_mfma_f32_16x16x32_bf16(af[i], bv, acc[i][j], 0, 0, 0);
      }
    }

    // phase 4: write staged kk+1 (loads had the MFMA phase to land)
    if (more) {
      *(uint4*)(&Bs2[nxt][rb*20 + hb*8])     = bn0;
      *(uint4*)(&Bs2[nxt][rb*20 + hb*8 + 4]) = bn1;
      if (tid < 320)
        Ws2[nxt][tid < 288 ? ((tid >> 5)*32 + (tid & 31)) : tid] = wv;
    }
    __syncthreads();   // barrier 2: Bs2[nxt]/Ws2[nxt] ready; As2 free
  }

  #pragma unroll
  for (int j = 0; j < 4; ++j) {
    int col = n0 + wn*64 + j*16 + l16;
    #pragma unroll
    for (int i = 0; i < 4; ++i) {
      #pragma unroll
      for (int r = 0; r < 4; ++r) {
        int row = m0 + wm*64 + i*16 + quad*4 + r;
        int bb = row / 100;
        int tt = row - bb*100;
        outp[(tt*128 + bb)*512 + col] = acc[i][j][r];
      }
    }
  }
}

// ---------------------------------------------------------------------------
// pv_xgadd: xg = sum of 4 K-partials + bih + bhh.  float4 grid-stride-free
// (grid 6400 x 256 covers 1,638,400 float4 exactly).
// ---------------------------------------------------------------------------
__global__ __launch_bounds__(256) void pv_xgadd(
    float* __restrict__ xg, const float* __restrict__ xgp,
    const float* __restrict__ bih, const float* __restrict__ bhh)
{
  const int i = blockIdx.x*256 + threadIdx.x;   // float4 index
  float4 a = ((const float4*)xg)[i];
  float4 b = ((const float4*)xgp)[i];
  float4 c = ((const float4*)xgp)[1638400 + i];
  float4 d = ((const float4*)xgp)[3276800 + i];
  const int col4 = (i & 127)*4;
  float4 bi = *(const float4*)(bih + col4);
  float4 bh = *(const float4*)(bhh + col4);
  float4 o;
  o.x = a.x + b.x + c.x + d.x + bi.x + bh.x;
  o.y = a.y + b.y + c.y + d.y + bi.y + bh.y;
  o.z = a.z + b.z + c.z + d.z + bi.z + bh.z;
  o.w = a.w + b.w + c.w + d.w + bi.w + bh.w;
  ((float4*)xg)[i] = o;
}

// ---------------------------------------------------------------------------
// pv_gemm: old fused path (fallback). Unchanged.
// ---------------------------------------------------------------------------
__global__ __launch_bounds__(256) void pv_gemm(
    const float* pose, const float* projW, const float* projb,
    const float* Wih, const float* bih, const float* bhh,
    float* xg)
{
  __shared__ __align__(16) unsigned As[128*24];
  __shared__ __align__(16) unsigned Bs[128*24];
  __shared__ float Ws[320];

  const int tid = threadIdx.x;
  const int m0 = blockIdx.x * 128;
  const int n0 = blockIdx.y * 128;

  const int rl = tid >> 1;
  const int kh = tid & 1;
  float p0,p1,p2,p3,p4,p5,p6,p7,p8;
  {
    const float* pr = pose + (m0 + rl) * 9;
    p0=pr[0]; p1=pr[1]; p2=pr[2]; p3=pr[3]; p4=pr[4];
    p5=pr[5]; p6=pr[6]; p7=pr[7]; p8=pr[8];
  }

  const int wave = tid >> 6;
  const int lane = tid & 63;
  const int wm = wave >> 1, wn = wave & 1;
  const int l16 = lane & 15, quad = lane >> 4;

  f32x4 acc[4][4];
  #pragma unroll
  for (int i = 0; i < 4; ++i)
    #pragma unroll
    for (int j = 0; j < 4; ++j) acc[i][j] = (f32x4){0.f,0.f,0.f,0.f};

  for (int kk = 0; kk < 128; ++kk) {
    __syncthreads();
    for (int idx = tid; idx < 320; idx += 256)
      Ws[idx] = (idx < 288) ? projW[kk*288 + idx] : projb[kk*32 + (idx - 288)];
    #pragma unroll
    for (int i = 0; i < 8; ++i) {
      int q = tid + i*256;
      int nl = q >> 4;
      int kp = q & 15;
      const float* src = Wih + (n0 + nl)*4096 + kk*32 + kp*2;
      Bs[nl*24 + kp] = pv_pack2(src[0], src[1]);
    }
    __syncthreads();
    {
      const int kbase = kh*16;
      const float* wbase = Ws + kbase*9;
      float av[16];
      #pragma unroll
      for (int u = 0; u < 16; ++u) {
        const float* wr = wbase + u*9;
        float s = Ws[288 + kbase + u]
                + p0*wr[0] + p1*wr[1] + p2*wr[2] + p3*wr[3] + p4*wr[4]
                + p5*wr[5] + p6*wr[6] + p7*wr[7] + p8*wr[8];
        av[u] = fmaxf(s, 0.1f*s);
      }
      #pragma unroll
      for (int q = 0; q < 8; ++q)
        As[rl*24 + kh*8 + q] = pv_pack2(av[2*q], av[2*q+1]);
    }
    __syncthreads();
    const unsigned short* As16 = (const unsigned short*)As;
    const unsigned short* Bs16 = (const unsigned short*)Bs;
    s16x8 af[4], bfv[4];
    #pragma unroll
    for (int i = 0; i < 4; ++i)
      af[i] = *(const s16x8*)(As16 + (wm*64 + i*16 + l16)*48 + quad*8);
    #pragma unroll
    for (int j = 0; j < 4; ++j)
      bfv[j] = *(const s16x8*)(Bs16 + (wn*64 + j*16 + l16)*48 + quad*8);
    #pragma unroll
    for (int i = 0; i < 4; ++i)
      #pragma unroll
      for (int j = 0; j < 4; ++j)
        acc[i][j] = __builtin_amdgcn_mfma_f32_16x16x32_bf16(af[i], bfv[j], acc[i][j], 0, 0, 0);
  }
  #pragma unroll
  for (int j = 0; j < 4; ++j) {
    int col = n0 + wn*64 + j*16 + l16;
    float bsum = bih[col] + bhh[col];
    #pragma unroll
    for (int i = 0; i < 4; ++i) {
      #pragma unroll
      for (int r = 0; r < 4; ++r) {
        int row = m0 + wm*64 + i*16 + quad*4 + r;
        int bb = row / 100;
        int tt = row - bb*100;
        xg[(tt*128 + bb)*512 + col] = acc[i][j][r] + bsum;
      }
    }
  }
}

// ---------------------------------------------------------------------------
// pv_lstm3: unchanged from round 13 (passed).
// ---------------------------------------------------------------------------
__global__ __launch_bounds__(512, 1) void pv_lstm3(
    const float* __restrict__ xg, const float* __restrict__ Whh,
    float* __restrict__ hT)
{
  __shared__ __align__(16) unsigned short Hs[16*136];  // [b16][u128+pad], rows 4+ = 0
  __shared__ __align__(16) float Ds[4*512];            // [b4][gate512]
  const int tid = threadIdx.x;
  const int wv = tid >> 6;           // 0..7
  const int lane = tid & 63;
  const int l16 = lane & 15, quad = lane >> 4;
  const int m0 = blockIdx.x * 4;
  const int j = wv*16 + l16;         // unit for MFMA B-frag

  s16x8 bfr[4][4];
  #pragma unroll
  for (int ty = 0; ty < 4; ++ty) {
    const int g = ty*128 + j;
    #pragma unroll
    for (int c = 0; c < 4; ++c) {
      s16x8 v;
      #pragma unroll
      for (int e = 0; e < 8; ++e)
        v[e] = (short)pv_f2b(Whh[g*128 + c*32 + quad*8 + e]);
      bfr[ty][c] = v;
    }
  }
  for (int i = tid; i < 16*136; i += 512) Hs[i] = 0;

  const int r_u = tid >> 7;          // 0..3
  const int j_u = tid & 127;         // 0..127
  float cst = 0.0f;
  const float* xbase = xg + (m0 + r_u)*512 + j_u;

  float xv[4];
  #pragma unroll
  for (int ty = 0; ty < 4; ++ty) xv[ty] = xbase[ty*128];
  __syncthreads();

  for (int t = 0; t < 100; ++t) {
    float xn[4];
    if (t < 99) {
      #pragma unroll
      for (int ty = 0; ty < 4; ++ty)
        xn[ty] = xbase[(t+1)*65536 + ty*128];
    }
    f32x4 acc[4];
    #pragma unroll
    for (int ty = 0; ty < 4; ++ty) acc[ty] = (f32x4){0.f,0.f,0.f,0.f};
    #pragma unroll
    for (int c = 0; c < 4; ++c) {
      s16x8 a = *(const s16x8*)(&Hs[l16*136 + c*32 + quad*8]);
      #pragma unroll
      for (int ty = 0; ty < 4; ++ty)
        acc[ty] = __builtin_amdgcn_mfma_f32_16x16x32_bf16(a, bfr[ty][c], acc[ty], 0, 0, 0);
    }
    if (quad == 0) {
      #pragma unroll
      for (int ty = 0; ty < 4; ++ty)
        #pragma unroll
        for (int r = 0; r < 4; ++r)
          Ds[r*512 + ty*128 + j] = acc[ty][r];
    }
    __syncthreads();   // barrier A: Ds ready, Hs reads done

    {
      const float* dsr = Ds + r_u*512;
      float gi = dsr[j_u]       + xv[0];
      float gf = dsr[128 + j_u] + xv[1];
      float gg = dsr[256 + j_u] + xv[2];
      float go = dsr[384 + j_u] + xv[3];
      float c_ = pv_sigm(gf)*cst + pv_sigm(gi)*pv_tanh(gg);
      cst = c_;
      float h = pv_sigm(go)*pv_tanh(c_);
      Hs[r_u*136 + j_u] = pv_f2b(h);
      if (t == 99) hT[(m0 + r_u)*128 + j_u] = h;
    }
    if (t < 99) {
      #pragma unroll
      for (int ty = 0; ty < 4; ++ty) xv[ty] = xn[ty];
    }
    __syncthreads();   // barrier B: Hs ready for next step
  }
}

// ---------------------------------------------------------------------------
// pv_head: unchanged.
// ---------------------------------------------------------------------------
__global__ __launch_bounds__(64) void pv_head(
    const float* hT, const float* eps,
    const float* muW, const float* mub,
    const float* lvW, const float* lvb,
    const float* fcW, const float* fcb,
    float* xvec, float* out)
{
  __shared__ float hrow[128];
  __shared__ float emb[64];
  const int b = blockIdx.x, j = threadIdx.x;
  hrow[j] = hT[b*128 + j];
  hrow[j + 64] = hT[b*128 + 64 + j];
  __syncthreads();
  float sm = mub[j], sl = lvb[j];
  for (int k = 0; k < 128; ++k) {
    sm += hrow[k]*muW[j*128 + k];
    sl += hrow[k]*lvW[j*128 + k];
  }
  float mu = fmaxf(sm, 0.1f*sm);
  float lv = fmaxf(sl, 0.1f*sl);
  lv = fminf(fmaxf(lv, -10.0f), 10.0f);
  float em = mu + eps[b*64 + j]*__expf(0.5f*lv);
  emb[j] = em;
  out[115200 + b*64 + j] = mu;
  out[123392 + b*64 + j] = lv;
  __syncthreads();
  for (int c4 = 0; c4 < 4; ++c4) {
    int c = c4*64 + j;
    float s = fcb[c];
    for (int k = 0; k < 64; ++k) s += emb[k]*fcW[c*64 + k];
    xvec[b*256 + c] = s;
  }
}

// ---------------------------------------------------------------------------
// pv_gxbase: unchanged.
// ---------------------------------------------------------------------------
__global__ __launch_bounds__(256) void pv_gxbase(
    const float* xvec, const float* Wih,
    const float* bih, const float* bhh, float* gxb)
{
  __shared__ float xs[8*256];
  const int tid = threadIdx.x;
  const int bg = blockIdx.x;
  const int gg = blockIdx.y;
  for (int i = tid; i < 2048; i += 256) xs[i] = xvec[bg*2048 + i];
  __syncthreads();
  const int g = gg*256 + tid;
  if (g >= 783) return;
  float bias = bih[g] + ((g < 522) ? bhh[g] : 0.0f);
  float a0=bias,a1=bias,a2=bias,a3=bias,a4=bias,a5=bias,a6=bias,a7=bias;
  const float* wr = Wih + g*261;
  for (int k = 0; k < 256; ++k) {
    float w = wr[k];
    a0 += xs[0*256 + k]*w; a1 += xs[1*256 + k]*w;
    a2 += xs[2*256 + k]*w; a3 += xs[3*256 + k]*w;
    a4 += xs[4*256 + k]*w; a5 += xs[5*256 + k]*w;
    a6 += xs[6*256 + k]*w; a7 += xs[7*256 + k]*w;
  }
  gxb[(bg*8 + 0)*783 + g] = a0; gxb[(bg*8 + 1)*783 + g] = a1;
  gxb[(bg*8 + 2)*783 + g] = a2; gxb[(bg*8 + 3)*783 + g] = a3;
  gxb[(bg*8 + 4)*783 + g] = a4; gxb[(bg*8 + 5)*783 + g] = a5;
  gxb[(bg*8 + 6)*783 + g] = a6; gxb[(bg*8 + 7)*783 + g] = a7;
}

// ---------------------------------------------------------------------------
// pv_gru5: byte-identical to the round-10/12/13 version (252-261us verified).
// ---------------------------------------------------------------------------
__global__ __launch_bounds__(512, 1) void pv_gru5(
    const float* __restrict__ gxb, const unsigned long long* __restrict__ wfp8,
    const float* __restrict__ Wih, const float* __restrict__ bhh,
    const float* __restrict__ noise, float* __restrict__ hseq)
{
  __shared__ __align__(16) unsigned long long Bl[27*9*64];   // 124,416 B
  __shared__ __align__(16) unsigned char A2[16*296];         //   4,736 B
  __shared__ __align__(16) float Ds[4*792];                  //  12,672 B
  const int tid = threadIdx.x;
  const int wv = tid >> 6;           // 0..7
  const int lane = tid & 63;
  const int l16 = lane & 15, quad = lane >> 4;
  const int m0 = blockIdx.x * 4;
  const int tailOwner = (wv >= 5);   // waves 5/6/7 own tail tiles 48/49/50

  // register B: tiles 3wv..3wv+2 (jb = wv, ty = 0..2)
  long bfr[3][9];
  #pragma unroll
  for (int s = 0; s < 3; ++s)
    #pragma unroll
    for (int c = 0; c < 9; ++c)
      bfr[s][c] = (long)wfp8[((3*wv + s)*9 + c)*64 + lane];
  #pragma unroll
  for (int s = 0; s < 3; ++s)
    #pragma unroll
    for (int c = 0; c < 9; ++c)
      asm volatile("" : "+v"(bfr[s][c]));

  // ---- per-thread update elements: (j1, r), (j2 = j1+128, r), tid<20: (j3, r)
  const int r_u = tid & 3;
  const int j1 = tid >> 2;           // 0..127
  const int j2 = 128 + j1;           // 128..255
  const int hasE3 = (tid < 20);
  const int j3 = 256 + (tid >> 2);   // 256..260 (valid when tid<20)
  float gx1[3], gx2[3], gx3[3], wn1[5], wn2[5], wn3[5];
  float bh1, bh2, bh3 = 0.f, h1 = 0.f, h2 = 0.f, h3 = 0.f;
  {
    const float* gb = gxb + (m0 + r_u)*783;
    gx1[0] = gb[j1]; gx1[1] = gb[261 + j1]; gx1[2] = gb[522 + j1];
    gx2[0] = gb[j2]; gx2[1] = gb[261 + j2]; gx2[2] = gb[522 + j2];
    const float* w1 = Wih + (522 + j1)*261 + 256;
    wn1[0] = 0.1f*w1[0]; wn1[1] = 0.1f*w1[1]; wn1[2] = 0.1f*w1[2];
    wn1[3] = 0.1f*w1[3]; wn1[4] = w1[4];
    const float* w2 = Wih + (522 + j2)*261 + 256;
    wn2[0] = 0.1f*w2[0]; wn2[1] = 0.1f*w2[1]; wn2[2] = 0.1f*w2[2];
    wn2[3] = 0.1f*w2[3]; wn2[4] = w2[4];
    bh1 = bhh[522 + j1];
    bh2 = bhh[522 + j2];
    #pragma unroll
    for (int k = 0; k < 3; ++k) gx3[k] = 0.f;
    #pragma unroll
    for (int k = 0; k < 5; ++k) wn3[k] = 0.f;
    if (hasE3) {
      gx3[0] = gb[j3]; gx3[1] = gb[261 + j3]; gx3[2] = gb[522 + j3];
      const float* w3 = Wih + (522 + j3)*261 + 256;
      wn3[0] = 0.1f*w3[0]; wn3[1] = 0.1f*w3[1]; wn3[2] = 0.1f*w3[2];
      wn3[3] = 0.1f*w3[3]; wn3[4] = w3[4];
      bh3 = bhh[522 + j3];
    }
  }

  // ---- stage LDS ----
  for (int i = tid; i < 27*9*64; i += 512) Bl[i] = wfp8[24*9*64 + i];
  for (int i = tid; i < 4736; i += 512) A2[i] = 0;
  __syncthreads();
  if (tid < 20) {   // t=0 noise/time cols (time_0 = 0)
    const int m = tid/5, i = tid - (tid/5)*5;
    float v = (i < 4) ? noise[(m0 + m)*4 + i]*0.1f : 0.0f;
    A2[m*296 + 261 + i] = pv_fp8(4.0f*v);
  }
  __syncthreads();

  const float inv32 = 1.0f/32.0f;
  const float* nptr = noise + (m0 + r_u)*4;
  for (int t = 0; t < 100; ++t) {
    // issue noise load early (independent of this step's compute)
    const float4 ne = *(const float4*)(nptr + t*512);

    f32x4 acc[7];
    #pragma unroll
    for (int s = 0; s < 7; ++s) acc[s] = (f32x4){0,0,0,0};
    #pragma unroll
    for (int c = 0; c < 9; ++c) {
      const long a = *(const long*)(&A2[l16*296 + c*32 + quad*8]);
      acc[0] = __builtin_amdgcn_mfma_f32_16x16x32_fp8_fp8(a, bfr[0][c], acc[0], 0, 0, 0);
      acc[1] = __builtin_amdgcn_mfma_f32_16x16x32_fp8_fp8(a, bfr[1][c], acc[1], 0, 0, 0);
      acc[2] = __builtin_amdgcn_mfma_f32_16x16x32_fp8_fp8(a, bfr[2][c], acc[2], 0, 0, 0);
      const long b3 = (long)Bl[((3*wv + 0)*9 + c)*64 + lane];
      const long b4 = (long)Bl[((3*wv + 1)*9 + c)*64 + lane];
      const long b5 = (long)Bl[((3*wv + 2)*9 + c)*64 + lane];
      acc[3] = __builtin_amdgcn_mfma_f32_16x16x32_fp8_fp8(a, b3, acc[3], 0, 0, 0);
      acc[4] = __builtin_amdgcn_mfma_f32_16x16x32_fp8_fp8(a, b4, acc[4], 0, 0, 0);
      acc[5] = __builtin_amdgcn_mfma_f32_16x16x32_fp8_fp8(a, b5, acc[5], 0, 0, 0);
      if (tailOwner) {
        const long b6 = (long)Bl[((24 + (wv - 5))*9 + c)*64 + lane];
        acc[6] = __builtin_amdgcn_mfma_f32_16x16x32_fp8_fp8(a, b6, acc[6], 0, 0, 0);
      }
    }
    // gate export: all owned tiles -> Ds[r][g]
    if (quad == 0) {
      #pragma unroll
      for (int s = 0; s < 3; ++s) {
        const int g = s*261 + wv*16 + l16;
        #pragma unroll
        for (int r = 0; r < 4; ++r) Ds[r*792 + g] = acc[s][r];
      }
      #pragma unroll
      for (int s = 0; s < 3; ++s) {
        const int g = s*261 + (8 + wv)*16 + l16;
        #pragma unroll
        for (int r = 0; r < 4; ++r) Ds[r*792 + g] = acc[3 + s][r];
      }
      if (tailOwner && l16 < 5) {
        const int g = (wv - 5)*261 + 256 + l16;
        #pragma unroll
        for (int r = 0; r < 4; ++r) Ds[r*792 + g] = acc[6][r];
      }
    }
    __syncthreads();   // barrier A: Ds complete, A2 reads done

    // ---- distributed update: elements (j1,r_u), (j2,r_u), [tid<20: (j3,r_u)]
    {
      const float tv = (float)t * (1.0f/99.0f);
      const float* dsr = Ds + r_u*792;
      {
        float Dr = dsr[j1]*inv32 + gx1[0];
        float Dz = dsr[261 + j1]*inv32 + gx1[1];
        float Dn = dsr[522 + j1]*inv32;
        float nterm = ne.x*wn1[0] + ne.y*wn1[1] + ne.z*wn1[2]
                    + ne.w*wn1[3] + tv*wn1[4];
        float r_ = pv_sigm(Dr);
        float z_ = pv_sigm(Dz);
        float n_ = pv_tanh(gx1[2] + nterm + r_*(Dn + bh1));
        h1 = (1.0f - z_)*n_ + z_*h1;
        hseq[(t*128 + m0 + r_u)*261 + j1] = h1;
        A2[r_u*296 + j1] = pv_fp8_fast(4.0f*h1);
      }
      {
        float Dr = dsr[j2]*inv32 + gx2[0];
        float Dz = dsr[261 + j2]*inv32 + gx2[1];
        float Dn = dsr[522 + j2]*inv32;
        float nterm = ne.x*wn2[0] + ne.y*wn2[1] + ne.z*wn2[2]
                    + ne.w*wn2[3] + tv*wn2[4];
        float r_ = pv_sigm(Dr);
        float z_ = pv_sigm(Dz);
        float n_ = pv_tanh(gx2[2] + nterm + r_*(Dn + bh2));
        h2 = (1.0f - z_)*n_ + z_*h2;
        hseq[(t*128 + m0 + r_u)*261 + j2] = h2;
        A2[r_u*296 + j2] = pv_fp8_fast(4.0f*h2);
      }
      if (hasE3) {
        float Dr = dsr[j3]*inv32 + gx3[0];
        float Dz = dsr[261 + j3]*inv32 + gx3[1];
        float Dn = dsr[522 + j3]*inv32;
        float nterm = ne.x*wn3[0] + ne.y*wn3[1] + ne.z*wn3[2]
                    + ne.w*wn3[3] + tv*wn3[4];
        float r_ = pv_sigm(Dr);
        float z_ = pv_sigm(Dz);
        float n_ = pv_tanh(gx3[2] + nterm + r_*(Dn + bh3));
        h3 = (1.0f - z_)*n_ + z_*h3;
        hseq[(t*128 + m0 + r_u)*261 + j3] = h3;
        A2[r_u*296 + j3] = pv_fp8_fast(4.0f*h3);
      }
    }
    // noise/time cols for t+1
    if (t < 99 && tid >= 40 && tid < 60) {
      const int k = tid - 40;
      const int m = k/5, i = k - (k/5)*5;
      float v = (i < 4) ? noise[((t+1)*128 + m0 + m)*4 + i]*0.1f
                        : (t+1)*(1.0f/99.0f);
      A2[m*296 + 261 + i] = pv_fp8(4.0f*v);
    }
    __syncthreads();   // barrier B: A2 ready for next step
  }
}

// ---------------------------------------------------------------------------
// pv_frames: unchanged.
// ---------------------------------------------------------------------------
__global__ __launch_bounds__(256) void pv_frames(
    const float* hseq, const float* W1, const float* b1,
    const float* W2, const float* b2, float* out)
{
  __shared__ __align__(16) float h16[16*264];
  __shared__ unsigned w1p[64*133];
  __shared__ float f1s[16*66];
  __shared__ float w2s[576];
  const int tid = threadIdx.x;
  const int r0 = blockIdx.x * 16;    // rows rt = t*128 + b
  for (int i = tid; i < 16*264; i += 256) {
    int r = i / 264, k = i - r*264;
    h16[i] = (k < 261) ? hseq[(r0 + r)*261 + k] : 0.0f;
  }
  for (int i = tid; i < 64*131; i += 256) {
    int c = i/131, kp = i - (i/131)*131;
    int k = kp*2;
    float a0 = W1[c*261 + k];
    float a1 = (k + 1 < 261) ? W1[c*261 + k + 1] : 0.0f;
    w1p[c*133 + kp] = pv_pack2(a0, a1);
  }
  for (int i = tid; i < 576; i += 256) w2s[i] = W2[i];
  __syncthreads();
  #pragma unroll
  for (int e = 0; e < 4; ++e) {
    const int el = tid + e*256;
    const int r = el >> 6, c = el & 63;
    float s = b1[c];
    const unsigned* wp = w1p + c*133;
    const float* hr = h16 + r*264;
    for (int kp = 0; kp < 131; ++kp) {
      unsigned w = wp[kp];
      s += pv_lo(w)*hr[2*kp] + pv_hi(w)*hr[2*kp + 1];
    }
    f1s[r*66 + c] = fmaxf(s, 0.2f*s);
  }
  __syncthreads();
  if (tid < 144) {
    const int r = tid/9, oc = tid - (tid/9)*9;
    float s = b2[oc];
    const float* fr = f1s + r*66;
    const float* w = w2s + oc*64;
    #pragma unroll 8
    for (int k = 0; k < 64; ++k) s += fr[k]*w[k];
    const int rt = r0 + r;
    const int tt = rt >> 7, bb = rt & 127;
    out[bb*900 + tt*9 + oc] = pv_sigm(s);
  }
}

// ---------------------------------------------------------------------------
extern "C" __attribute__((visibility("default")))
void kernel_launch(void* const* d_in, const int* in_sizes, int n_in,
                   void* d_out, int out_size, void* d_ws, size_t ws_size,
                   hipStream_t stream)
{
  (void)in_sizes; (void)n_in; (void)out_size;
  const float* input_data = (const float*)d_in[0];
  const float* eps        = (const float*)d_in[1];
  const float* noise_eps  = (const float*)d_in[2];
  const float* proj_W     = (const float*)d_in[3];
  const float* proj_b     = (const float*)d_in[4];
  const float* lstm_Wih   = (const float*)d_in[5];
  const float* lstm_Whh   = (const float*)d_in[6];
  const float* lstm_bih   = (const float*)d_in[7];
  const float* lstm_bhh   = (const float*)d_in[8];
  const float* mu_W       = (const float*)d_in[9];
  const float* mu_b       = (const float*)d_in[10];
  const float* lv_W       = (const float*)d_in[11];
  const float* lv_b       = (const float*)d_in[12];
  const float* fcin_W     = (const float*)d_in[13];
  const float* fcin_b     = (const float*)d_in[14];
  const float* gru_Wih    = (const float*)d_in[15];
  const float* gru_Whh    = (const float*)d_in[16];
  const float* gru_bih    = (const float*)d_in[17];
  const float* gru_bhh    = (const float*)d_in[18];
  const float* jf_W1      = (const float*)d_in[19];
  const float* jf_b1      = (const float*)d_in[20];
  const float* jf_W2      = (const float*)d_in[21];
  const float* jf_b2      = (const float*)d_in[22];

  char* w = (char*)d_ws;
  float*              xg   = (float*)(w);                          // 26,214,400 B
  unsigned long long* wfp8 = (unsigned long long*)(w + 26214400);  //    235,008 B
  float*              hT   = (float*)(w + 26449408);               //     65,536 B
  float*              xvec = (float*)(w + 26514944);               //    131,072 B
  float*              gxb  = (float*)(w + 26646016);               //    400,896 B
  float*              hseq = (float*)(w + 27046912);               // 13,363,200 B (end 40,410,112)
  unsigned*           wihb = (unsigned*)(w + 40410112);            //  4,194,304 B (end 44,604,416)
  float*              xgp  = (float*)(w + 44604416);               // 78,643,200 B (end 123,247,616)
  float*              outf = (float*)d_out;

  const int use_split = (ws_size >= (size_t)123247616ull);

  pv_prep_gru8<<<115, 256, 0, stream>>>(gru_Whh, gru_Wih, wfp8);
  if (use_split) {
    pv_prep_wih<<<1024, 256, 0, stream>>>(lstm_Wih, wihb);
    pv_gemm4k<<<dim3(100, 2, 4), 512, 0, stream>>>(input_data, proj_W, proj_b,
                                                   wihb, xg, xgp);
    pv_xgadd<<<6400, 256, 0, stream>>>(xg, xgp, lstm_bih, lstm_bhh);
  } else {
    pv_gemm<<<dim3(100, 4), 256, 0, stream>>>(input_data, proj_W, proj_b,
                                              lstm_Wih, lstm_bih, lstm_bhh, xg);
  }
  pv_lstm3<<<32, 512, 0, stream>>>(xg, lstm_Whh, hT);
  pv_head<<<128, 64, 0, stream>>>(hT, eps, mu_W, mu_b, lv_W, lv_b,
                                  fcin_W, fcin_b, xvec, outf);
  pv_gxbase<<<dim3(16, 4), 256, 0, stream>>>(xvec, gru_Wih, gru_bih, gru_bhh, gxb);
  pv_gru5<<<32, 512, 0, stream>>>(gxb, wfp8, gru_Wih, gru_bhh, noise_eps, hseq);
  pv_frames<<<800, 256, 0, stream>>>(hseq, jf_W1, jf_b1, jf_W2, jf_b2, outf);
}

// Round 15
// 679.764 us; speedup vs baseline: 1.0602x; 1.0602x over previous
//
#include <hip/hip_runtime.h>
#include <hip/hip_bf16.h>

typedef float f32x4 __attribute__((ext_vector_type(4)));
typedef short s16x8 __attribute__((ext_vector_type(8)));

__device__ __forceinline__ float pv_sigm(float x){ return 1.0f/(1.0f + __expf(-x)); }
__device__ __forceinline__ float pv_tanh(float x){ float e = __expf(2.0f*x); return 1.0f - 2.0f/(e + 1.0f); }

__device__ __forceinline__ unsigned short pv_f2b(float x){
  union { float f; unsigned u; } c; c.f = x;
  unsigned r = (c.u + 0x7fffu + ((c.u >> 16) & 1u)) >> 16;
  return (unsigned short)r;
}
__device__ __forceinline__ unsigned pv_pack2(float a, float b){
  return ((unsigned)pv_f2b(b) << 16) | (unsigned)pv_f2b(a);
}
__device__ __forceinline__ float pv_lo(unsigned u){
  union { unsigned u; float f; } c; c.u = u << 16; return c.f;
}
__device__ __forceinline__ float pv_hi(unsigned u){
  union { unsigned u; float f; } c; c.u = u & 0xffff0000u; return c.f;
}

// manual OCP e4m3fn encode (RNE); valid for |x| < 448
__device__ __forceinline__ unsigned char pv_fp8(float x){
  union { float f; unsigned u; } c; c.f = x;
  unsigned s = (c.u >> 24) & 0x80u;
  unsigned au = c.u & 0x7fffffffu;
  if (au == 0u) return (unsigned char)s;
  int ex = (int)(au >> 23) - 127;
  if (ex < -6) ex = -6;
  union { unsigned u; float f; } iv; iv.u = (unsigned)(3 - ex + 127) << 23;
  union { unsigned u; float f; } a;  a.u = au;
  int q = (int)rintf(a.f * iv.f);
  if (q >= 16) { q >>= 1; ex += 1; }
  unsigned bits;
  if (ex == -6 && q < 8) bits = (unsigned)q;
  else bits = (unsigned)(((ex + 7) << 3) | (q - 8));
  return (unsigned char)(s | bits);
}

#if defined(__has_builtin)
#if __has_builtin(__builtin_amdgcn_cvt_pk_fp8_f32)
#define PV_HW_FP8 1
#endif
#endif
__device__ __forceinline__ unsigned char pv_fp8_fast(float x){
#ifdef PV_HW_FP8
  return (unsigned char)__builtin_amdgcn_cvt_pk_fp8_f32(x, x, 0, false);
#else
  return pv_fp8(x);
#endif
}

// ---------------------------------------------------------------------------
// pv_prep_gru8: unchanged (verified r4-r14).
// ---------------------------------------------------------------------------
__global__ void pv_prep_gru8(const float* Whh, const float* Wih,
                             unsigned long long* wfp8){
  int idx = blockIdx.x*256 + threadIdx.x;   // < 51*9*64 = 29376
  if (idx >= 29376) return;
  int T = idx / 576;
  int rem = idx - T*576;
  int c = rem >> 6;
  int l = rem & 63;
  int l16 = l & 15;
  int quad = l >> 4;
  int jb = T / 3;
  int ty = T - jb*3;
  int j = jb*16 + l16;
  int g = ty*261 + j;
  unsigned long long v = 0ull;
  #pragma unroll
  for (int e = 0; e < 8; ++e) {
    int k = c*32 + quad*8 + e;
    float w = 0.0f;
    if (j < 261) {
      if (k < 261) w = Whh[g*261 + k];
      else if (k < 266 && ty < 2) w = Wih[g*261 + 256 + (k - 261)];
    }
    v |= (unsigned long long)pv_fp8(8.0f*w) << (8*e);
  }
  wfp8[idx] = v;
}

// ---------------------------------------------------------------------------
// pv_prep_wih: unchanged.
// ---------------------------------------------------------------------------
__global__ __launch_bounds__(256) void pv_prep_wih(
    const float* __restrict__ Wih, unsigned* __restrict__ wihb)
{
  const int idx = blockIdx.x*256 + threadIdx.x;      // 262144 threads
  if (idx >= 262144) return;
  const float* src = Wih + idx*8;
  float4 a = *(const float4*)(src);
  float4 b = *(const float4*)(src + 4);
  uint4 o;
  o.x = pv_pack2(a.x, a.y);
  o.y = pv_pack2(a.z, a.w);
  o.z = pv_pack2(b.x, b.y);
  o.w = pv_pack2(b.z, b.w);
  *(uint4*)(wihb + idx*4) = o;
}

// ---------------------------------------------------------------------------
// pv_gemm4: reverted to the round-12/13 version (verified 677.6us total).
// r14's K-split (gemm4k + xgadd) regressed (+43us): gemm4's cost is NOT
// exposed-barrier serialization hideable by TLP; the split's overheads
// (partial traffic + reduction pass) were pure loss.
// ---------------------------------------------------------------------------
__global__ __launch_bounds__(512, 1) void pv_gemm4(
    const float* __restrict__ pose, const float* __restrict__ projW,
    const float* __restrict__ projb, const unsigned* __restrict__ wihb,
    const float* __restrict__ bih, const float* __restrict__ bhh,
    float* __restrict__ xg)
{
  __shared__ __align__(16) unsigned As2[128*20];      // A bf16 [128][40s]
  __shared__ __align__(16) unsigned Bs2[2][256*20];   // B bf16 [256][40s], dbuf
  __shared__ __align__(16) float Ws2[2][320];         // W^T: [j*32+kl], bias 288+

  const int tid = threadIdx.x;
  const int m0 = blockIdx.x * 128;
  const int n0 = blockIdx.y * 256;
  const int wave = tid >> 6, lane = tid & 63;
  const int wm = wave >> 2, wn = wave & 3;
  const int l16 = lane & 15, quad = lane >> 4;
  const int rl = tid >> 2, kq = tid & 3;       // A-gen: row rl, k-quarter kq
  const int rb = tid >> 1, hb = tid & 1;       // B-stage: row rb, half hb

  float p[9];
  {
    const float* pr = pose + (m0 + rl)*9;
    #pragma unroll
    for (int j = 0; j < 9; ++j) p[j] = pr[j];
  }

  if (tid < 320) {
    Ws2[0][tid < 288 ? ((tid >> 5)*32 + (tid & 31)) : tid] =
        (tid < 288) ? projW[(tid & 31)*9 + (tid >> 5)] : projb[tid - 288];
  }
  {
    const unsigned* src = wihb + (n0 + rb)*2048 + hb*8;
    *(uint4*)(&Bs2[0][rb*20 + hb*8])     = *(const uint4*)(src);
    *(uint4*)(&Bs2[0][rb*20 + hb*8 + 4]) = *(const uint4*)(src + 4);
  }
  __syncthreads();

  f32x4 acc[4][4];
  #pragma unroll
  for (int i = 0; i < 4; ++i)
    #pragma unroll
    for (int j = 0; j < 4; ++j) acc[i][j] = (f32x4){0.f,0.f,0.f,0.f};

  for (int kk = 0; kk < 128; ++kk) {
    const int cur = kk & 1, nxt = cur ^ 1;
    const int kn = kk + 1;

    // phase 1: issue loads for kk+1 (in flight through MFMA phase)
    uint4 bn0, bn1; float wv = 0.0f;
    if (kn < 128) {
      const unsigned* bsrc = wihb + (n0 + rb)*2048 + kn*16 + hb*8;
      bn0 = *(const uint4*)(bsrc);
      bn1 = *(const uint4*)(bsrc + 4);
      if (tid < 320)
        wv = (tid < 288) ? projW[kn*288 + (tid & 31)*9 + (tid >> 5)]
                         : projb[kn*32 + (tid - 288)];
    }

    // phase 2: A-gen for kk (bit-identical math)
    {
      const float* W = Ws2[cur];
      f32x4 slo = *(const f32x4*)(W + 288 + kq*8);
      f32x4 shi = *(const f32x4*)(W + 292 + kq*8);
      #pragma unroll
      for (int j = 0; j < 9; ++j) {
        f32x4 wlo = *(const f32x4*)(W + j*32 + kq*8);
        f32x4 whi = *(const f32x4*)(W + j*32 + kq*8 + 4);
        slo += p[j]*wlo;
        shi += p[j]*whi;
      }
      #pragma unroll
      for (int e = 0; e < 4; ++e) {
        slo[e] = fmaxf(slo[e], 0.1f*slo[e]);
        shi[e] = fmaxf(shi[e], 0.1f*shi[e]);
      }
      uint4 av;
      av.x = pv_pack2(slo[0], slo[1]);
      av.y = pv_pack2(slo[2], slo[3]);
      av.z = pv_pack2(shi[0], shi[1]);
      av.w = pv_pack2(shi[2], shi[3]);
      *(uint4*)(&As2[rl*20 + kq*4]) = av;
    }
    __syncthreads();   // barrier 1: As2 ready

    // phase 3: MFMA for kk
    {
      const unsigned short* As16 = (const unsigned short*)As2;
      const unsigned short* Bs16 = (const unsigned short*)Bs2[cur];
      s16x8 af[4];
      #pragma unroll
      for (int i = 0; i < 4; ++i)
        af[i] = *(const s16x8*)(As16 + (wm*64 + i*16 + l16)*40 + quad*8);
      #pragma unroll
      for (int j = 0; j < 4; ++j) {
        s16x8 bv = *(const s16x8*)(Bs16 + (wn*64 + j*16 + l16)*40 + quad*8);
        #pragma unroll
        for (int i = 0; i < 4; ++i)
          acc[i][j] = __builtin_amdgcn_mfma_f32_16x16x32_bf16(af[i], bv, acc[i][j], 0, 0, 0);
      }
    }

    // phase 4: write staged kk+1 (loads had the MFMA phase to land)
    if (kn < 128) {
      *(uint4*)(&Bs2[nxt][rb*20 + hb*8])     = bn0;
      *(uint4*)(&Bs2[nxt][rb*20 + hb*8 + 4]) = bn1;
      if (tid < 320)
        Ws2[nxt][tid < 288 ? ((tid >> 5)*32 + (tid & 31)) : tid] = wv;
    }
    __syncthreads();   // barrier 2: Bs2[nxt]/Ws2[nxt] ready; As2 free
  }

  #pragma unroll
  for (int j = 0; j < 4; ++j) {
    int col = n0 + wn*64 + j*16 + l16;
    float bsum = bih[col] + bhh[col];
    #pragma unroll
    for (int i = 0; i < 4; ++i) {
      #pragma unroll
      for (int r = 0; r < 4; ++r) {
        int row = m0 + wm*64 + i*16 + quad*4 + r;
        int bb = row / 100;
        int tt = row - bb*100;
        xg[(tt*128 + bb)*512 + col] = acc[i][j][r] + bsum;
      }
    }
  }
}

// ---------------------------------------------------------------------------
// pv_gemm: old fused path (fallback). Unchanged.
// ---------------------------------------------------------------------------
__global__ __launch_bounds__(256) void pv_gemm(
    const float* pose, const float* projW, const float* projb,
    const float* Wih, const float* bih, const float* bhh,
    float* xg)
{
  __shared__ __align__(16) unsigned As[128*24];
  __shared__ __align__(16) unsigned Bs[128*24];
  __shared__ float Ws[320];

  const int tid = threadIdx.x;
  const int m0 = blockIdx.x * 128;
  const int n0 = blockIdx.y * 128;

  const int rl = tid >> 1;
  const int kh = tid & 1;
  float p0,p1,p2,p3,p4,p5,p6,p7,p8;
  {
    const float* pr = pose + (m0 + rl) * 9;
    p0=pr[0]; p1=pr[1]; p2=pr[2]; p3=pr[3]; p4=pr[4];
    p5=pr[5]; p6=pr[6]; p7=pr[7]; p8=pr[8];
  }

  const int wave = tid >> 6;
  const int lane = tid & 63;
  const int wm = wave >> 1, wn = wave & 1;
  const int l16 = lane & 15, quad = lane >> 4;

  f32x4 acc[4][4];
  #pragma unroll
  for (int i = 0; i < 4; ++i)
    #pragma unroll
    for (int j = 0; j < 4; ++j) acc[i][j] = (f32x4){0.f,0.f,0.f,0.f};

  for (int kk = 0; kk < 128; ++kk) {
    __syncthreads();
    for (int idx = tid; idx < 320; idx += 256)
      Ws[idx] = (idx < 288) ? projW[kk*288 + idx] : projb[kk*32 + (idx - 288)];
    #pragma unroll
    for (int i = 0; i < 8; ++i) {
      int q = tid + i*256;
      int nl = q >> 4;
      int kp = q & 15;
      const float* src = Wih + (n0 + nl)*4096 + kk*32 + kp*2;
      Bs[nl*24 + kp] = pv_pack2(src[0], src[1]);
    }
    __syncthreads();
    {
      const int kbase = kh*16;
      const float* wbase = Ws + kbase*9;
      float av[16];
      #pragma unroll
      for (int u = 0; u < 16; ++u) {
        const float* wr = wbase + u*9;
        float s = Ws[288 + kbase + u]
                + p0*wr[0] + p1*wr[1] + p2*wr[2] + p3*wr[3] + p4*wr[4]
                + p5*wr[5] + p6*wr[6] + p7*wr[7] + p8*wr[8];
        av[u] = fmaxf(s, 0.1f*s);
      }
      #pragma unroll
      for (int q = 0; q < 8; ++q)
        As[rl*24 + kh*8 + q] = pv_pack2(av[2*q], av[2*q+1]);
    }
    __syncthreads();
    const unsigned short* As16 = (const unsigned short*)As;
    const unsigned short* Bs16 = (const unsigned short*)Bs;
    s16x8 af[4], bfv[4];
    #pragma unroll
    for (int i = 0; i < 4; ++i)
      af[i] = *(const s16x8*)(As16 + (wm*64 + i*16 + l16)*48 + quad*8);
    #pragma unroll
    for (int j = 0; j < 4; ++j)
      bfv[j] = *(const s16x8*)(Bs16 + (wn*64 + j*16 + l16)*48 + quad*8);
    #pragma unroll
    for (int i = 0; i < 4; ++i)
      #pragma unroll
      for (int j = 0; j < 4; ++j)
        acc[i][j] = __builtin_amdgcn_mfma_f32_16x16x32_bf16(af[i], bfv[j], acc[i][j], 0, 0, 0);
  }
  #pragma unroll
  for (int j = 0; j < 4; ++j) {
    int col = n0 + wn*64 + j*16 + l16;
    float bsum = bih[col] + bhh[col];
    #pragma unroll
    for (int i = 0; i < 4; ++i) {
      #pragma unroll
      for (int r = 0; r < 4; ++r) {
        int row = m0 + wm*64 + i*16 + quad*4 + r;
        int bb = row / 100;
        int tt = row - bb*100;
        xg[(tt*128 + bb)*512 + col] = acc[i][j][r] + bsum;
      }
    }
  }
}

// ---------------------------------------------------------------------------
// pv_lstm3: unchanged from round 13 (passed).
// ---------------------------------------------------------------------------
__global__ __launch_bounds__(512, 1) void pv_lstm3(
    const float* __restrict__ xg, const float* __restrict__ Whh,
    float* __restrict__ hT)
{
  __shared__ __align__(16) unsigned short Hs[16*136];  // [b16][u128+pad], rows 4+ = 0
  __shared__ __align__(16) float Ds[4*512];            // [b4][gate512]
  const int tid = threadIdx.x;
  const int wv = tid >> 6;           // 0..7
  const int lane = tid & 63;
  const int l16 = lane & 15, quad = lane >> 4;
  const int m0 = blockIdx.x * 4;
  const int j = wv*16 + l16;         // unit for MFMA B-frag

  s16x8 bfr[4][4];
  #pragma unroll
  for (int ty = 0; ty < 4; ++ty) {
    const int g = ty*128 + j;
    #pragma unroll
    for (int c = 0; c < 4; ++c) {
      s16x8 v;
      #pragma unroll
      for (int e = 0; e < 8; ++e)
        v[e] = (short)pv_f2b(Whh[g*128 + c*32 + quad*8 + e]);
      bfr[ty][c] = v;
    }
  }
  for (int i = tid; i < 16*136; i += 512) Hs[i] = 0;

  const int r_u = tid >> 7;          // 0..3
  const int j_u = tid & 127;         // 0..127
  float cst = 0.0f;
  const float* xbase = xg + (m0 + r_u)*512 + j_u;

  float xv[4];
  #pragma unroll
  for (int ty = 0; ty < 4; ++ty) xv[ty] = xbase[ty*128];
  __syncthreads();

  for (int t = 0; t < 100; ++t) {
    float xn[4];
    if (t < 99) {
      #pragma unroll
      for (int ty = 0; ty < 4; ++ty)
        xn[ty] = xbase[(t+1)*65536 + ty*128];
    }
    f32x4 acc[4];
    #pragma unroll
    for (int ty = 0; ty < 4; ++ty) acc[ty] = (f32x4){0.f,0.f,0.f,0.f};
    #pragma unroll
    for (int c = 0; c < 4; ++c) {
      s16x8 a = *(const s16x8*)(&Hs[l16*136 + c*32 + quad*8]);
      #pragma unroll
      for (int ty = 0; ty < 4; ++ty)
        acc[ty] = __builtin_amdgcn_mfma_f32_16x16x32_bf16(a, bfr[ty][c], acc[ty], 0, 0, 0);
    }
    if (quad == 0) {
      #pragma unroll
      for (int ty = 0; ty < 4; ++ty)
        #pragma unroll
        for (int r = 0; r < 4; ++r)
          Ds[r*512 + ty*128 + j] = acc[ty][r];
    }
    __syncthreads();   // barrier A: Ds ready, Hs reads done

    {
      const float* dsr = Ds + r_u*512;
      float gi = dsr[j_u]       + xv[0];
      float gf = dsr[128 + j_u] + xv[1];
      float gg = dsr[256 + j_u] + xv[2];
      float go = dsr[384 + j_u] + xv[3];
      float c_ = pv_sigm(gf)*cst + pv_sigm(gi)*pv_tanh(gg);
      cst = c_;
      float h = pv_sigm(go)*pv_tanh(c_);
      Hs[r_u*136 + j_u] = pv_f2b(h);
      if (t == 99) hT[(m0 + r_u)*128 + j_u] = h;
    }
    if (t < 99) {
      #pragma unroll
      for (int ty = 0; ty < 4; ++ty) xv[ty] = xn[ty];
    }
    __syncthreads();   // barrier B: Hs ready for next step
  }
}

// ---------------------------------------------------------------------------
// pv_head: unchanged.
// ---------------------------------------------------------------------------
__global__ __launch_bounds__(64) void pv_head(
    const float* hT, const float* eps,
    const float* muW, const float* mub,
    const float* lvW, const float* lvb,
    const float* fcW, const float* fcb,
    float* xvec, float* out)
{
  __shared__ float hrow[128];
  __shared__ float emb[64];
  const int b = blockIdx.x, j = threadIdx.x;
  hrow[j] = hT[b*128 + j];
  hrow[j + 64] = hT[b*128 + 64 + j];
  __syncthreads();
  float sm = mub[j], sl = lvb[j];
  for (int k = 0; k < 128; ++k) {
    sm += hrow[k]*muW[j*128 + k];
    sl += hrow[k]*lvW[j*128 + k];
  }
  float mu = fmaxf(sm, 0.1f*sm);
  float lv = fmaxf(sl, 0.1f*sl);
  lv = fminf(fmaxf(lv, -10.0f), 10.0f);
  float em = mu + eps[b*64 + j]*__expf(0.5f*lv);
  emb[j] = em;
  out[115200 + b*64 + j] = mu;
  out[123392 + b*64 + j] = lv;
  __syncthreads();
  for (int c4 = 0; c4 < 4; ++c4) {
    int c = c4*64 + j;
    float s = fcb[c];
    for (int k = 0; k < 64; ++k) s += emb[k]*fcW[c*64 + k];
    xvec[b*256 + c] = s;
  }
}

// ---------------------------------------------------------------------------
// pv_gxbase: unchanged.
// ---------------------------------------------------------------------------
__global__ __launch_bounds__(256) void pv_gxbase(
    const float* xvec, const float* Wih,
    const float* bih, const float* bhh, float* gxb)
{
  __shared__ float xs[8*256];
  const int tid = threadIdx.x;
  const int bg = blockIdx.x;
  const int gg = blockIdx.y;
  for (int i = tid; i < 2048; i += 256) xs[i] = xvec[bg*2048 + i];
  __syncthreads();
  const int g = gg*256 + tid;
  if (g >= 783) return;
  float bias = bih[g] + ((g < 522) ? bhh[g] : 0.0f);
  float a0=bias,a1=bias,a2=bias,a3=bias,a4=bias,a5=bias,a6=bias,a7=bias;
  const float* wr = Wih + g*261;
  for (int k = 0; k < 256; ++k) {
    float w = wr[k];
    a0 += xs[0*256 + k]*w; a1 += xs[1*256 + k]*w;
    a2 += xs[2*256 + k]*w; a3 += xs[3*256 + k]*w;
    a4 += xs[4*256 + k]*w; a5 += xs[5*256 + k]*w;
    a6 += xs[6*256 + k]*w; a7 += xs[7*256 + k]*w;
  }
  gxb[(bg*8 + 0)*783 + g] = a0; gxb[(bg*8 + 1)*783 + g] = a1;
  gxb[(bg*8 + 2)*783 + g] = a2; gxb[(bg*8 + 3)*783 + g] = a3;
  gxb[(bg*8 + 4)*783 + g] = a4; gxb[(bg*8 + 5)*783 + g] = a5;
  gxb[(bg*8 + 6)*783 + g] = a6; gxb[(bg*8 + 7)*783 + g] = a7;
}

// ---------------------------------------------------------------------------
// pv_gru5: byte-identical to the round-10/12/13 version (252-261us verified).
// ---------------------------------------------------------------------------
__global__ __launch_bounds__(512, 1) void pv_gru5(
    const float* __restrict__ gxb, const unsigned long long* __restrict__ wfp8,
    const float* __restrict__ Wih, const float* __restrict__ bhh,
    const float* __restrict__ noise, float* __restrict__ hseq)
{
  __shared__ __align__(16) unsigned long long Bl[27*9*64];   // 124,416 B
  __shared__ __align__(16) unsigned char A2[16*296];         //   4,736 B
  __shared__ __align__(16) float Ds[4*792];                  //  12,672 B
  const int tid = threadIdx.x;
  const int wv = tid >> 6;           // 0..7
  const int lane = tid & 63;
  const int l16 = lane & 15, quad = lane >> 4;
  const int m0 = blockIdx.x * 4;
  const int tailOwner = (wv >= 5);   // waves 5/6/7 own tail tiles 48/49/50

  // register B: tiles 3wv..3wv+2 (jb = wv, ty = 0..2)
  long bfr[3][9];
  #pragma unroll
  for (int s = 0; s < 3; ++s)
    #pragma unroll
    for (int c = 0; c < 9; ++c)
      bfr[s][c] = (long)wfp8[((3*wv + s)*9 + c)*64 + lane];
  #pragma unroll
  for (int s = 0; s < 3; ++s)
    #pragma unroll
    for (int c = 0; c < 9; ++c)
      asm volatile("" : "+v"(bfr[s][c]));

  // ---- per-thread update elements: (j1, r), (j2 = j1+128, r), tid<20: (j3, r)
  const int r_u = tid & 3;
  const int j1 = tid >> 2;           // 0..127
  const int j2 = 128 + j1;           // 128..255
  const int hasE3 = (tid < 20);
  const int j3 = 256 + (tid >> 2);   // 256..260 (valid when tid<20)
  float gx1[3], gx2[3], gx3[3], wn1[5], wn2[5], wn3[5];
  float bh1, bh2, bh3 = 0.f, h1 = 0.f, h2 = 0.f, h3 = 0.f;
  {
    const float* gb = gxb + (m0 + r_u)*783;
    gx1[0] = gb[j1]; gx1[1] = gb[261 + j1]; gx1[2] = gb[522 + j1];
    gx2[0] = gb[j2]; gx2[1] = gb[261 + j2]; gx2[2] = gb[522 + j2];
    const float* w1 = Wih + (522 + j1)*261 + 256;
    wn1[0] = 0.1f*w1[0]; wn1[1] = 0.1f*w1[1]; wn1[2] = 0.1f*w1[2];
    wn1[3] = 0.1f*w1[3]; wn1[4] = w1[4];
    const float* w2 = Wih + (522 + j2)*261 + 256;
    wn2[0] = 0.1f*w2[0]; wn2[1] = 0.1f*w2[1]; wn2[2] = 0.1f*w2[2];
    wn2[3] = 0.1f*w2[3]; wn2[4] = w2[4];
    bh1 = bhh[522 + j1];
    bh2 = bhh[522 + j2];
    #pragma unroll
    for (int k = 0; k < 3; ++k) gx3[k] = 0.f;
    #pragma unroll
    for (int k = 0; k < 5; ++k) wn3[k] = 0.f;
    if (hasE3) {
      gx3[0] = gb[j3]; gx3[1] = gb[261 + j3]; gx3[2] = gb[522 + j3];
      const float* w3 = Wih + (522 + j3)*261 + 256;
      wn3[0] = 0.1f*w3[0]; wn3[1] = 0.1f*w3[1]; wn3[2] = 0.1f*w3[2];
      wn3[3] = 0.1f*w3[3]; wn3[4] = w3[4];
      bh3 = bhh[522 + j3];
    }
  }

  // ---- stage LDS ----
  for (int i = tid; i < 27*9*64; i += 512) Bl[i] = wfp8[24*9*64 + i];
  for (int i = tid; i < 4736; i += 512) A2[i] = 0;
  __syncthreads();
  if (tid < 20) {   // t=0 noise/time cols (time_0 = 0)
    const int m = tid/5, i = tid - (tid/5)*5;
    float v = (i < 4) ? noise[(m0 + m)*4 + i]*0.1f : 0.0f;
    A2[m*296 + 261 + i] = pv_fp8(4.0f*v);
  }
  __syncthreads();

  const float inv32 = 1.0f/32.0f;
  const float* nptr = noise + (m0 + r_u)*4;
  for (int t = 0; t < 100; ++t) {
    // issue noise load early (independent of this step's compute)
    const float4 ne = *(const float4*)(nptr + t*512);

    f32x4 acc[7];
    #pragma unroll
    for (int s = 0; s < 7; ++s) acc[s] = (f32x4){0,0,0,0};
    #pragma unroll
    for (int c = 0; c < 9; ++c) {
      const long a = *(const long*)(&A2[l16*296 + c*32 + quad*8]);
      acc[0] = __builtin_amdgcn_mfma_f32_16x16x32_fp8_fp8(a, bfr[0][c], acc[0], 0, 0, 0);
      acc[1] = __builtin_amdgcn_mfma_f32_16x16x32_fp8_fp8(a, bfr[1][c], acc[1], 0, 0, 0);
      acc[2] = __builtin_amdgcn_mfma_f32_16x16x32_fp8_fp8(a, bfr[2][c], acc[2], 0, 0, 0);
      const long b3 = (long)Bl[((3*wv + 0)*9 + c)*64 + lane];
      const long b4 = (long)Bl[((3*wv + 1)*9 + c)*64 + lane];
      const long b5 = (long)Bl[((3*wv + 2)*9 + c)*64 + lane];
      acc[3] = __builtin_amdgcn_mfma_f32_16x16x32_fp8_fp8(a, b3, acc[3], 0, 0, 0);
      acc[4] = __builtin_amdgcn_mfma_f32_16x16x32_fp8_fp8(a, b4, acc[4], 0, 0, 0);
      acc[5] = __builtin_amdgcn_mfma_f32_16x16x32_fp8_fp8(a, b5, acc[5], 0, 0, 0);
      if (tailOwner) {
        const long b6 = (long)Bl[((24 + (wv - 5))*9 + c)*64 + lane];
        acc[6] = __builtin_amdgcn_mfma_f32_16x16x32_fp8_fp8(a, b6, acc[6], 0, 0, 0);
      }
    }
    // gate export: all owned tiles -> Ds[r][g]
    if (quad == 0) {
      #pragma unroll
      for (int s = 0; s < 3; ++s) {
        const int g = s*261 + wv*16 + l16;
        #pragma unroll
        for (int r = 0; r < 4; ++r) Ds[r*792 + g] = acc[s][r];
      }
      #pragma unroll
      for (int s = 0; s < 3; ++s) {
        const int g = s*261 + (8 + wv)*16 + l16;
        #pragma unroll
        for (int r = 0; r < 4; ++r) Ds[r*792 + g] = acc[3 + s][r];
      }
      if (tailOwner && l16 < 5) {
        const int g = (wv - 5)*261 + 256 + l16;
        #pragma unroll
        for (int r = 0; r < 4; ++r) Ds[r*792 + g] = acc[6][r];
      }
    }
    __syncthreads();   // barrier A: Ds complete, A2 reads done

    // ---- distributed update: elements (j1,r_u), (j2,r_u), [tid<20: (j3,r_u)]
    {
      const float tv = (float)t * (1.0f/99.0f);
      const float* dsr = Ds + r_u*792;
      {
        float Dr = dsr[j1]*inv32 + gx1[0];
        float Dz = dsr[261 + j1]*inv32 + gx1[1];
        float Dn = dsr[522 + j1]*inv32;
        float nterm = ne.x*wn1[0] + ne.y*wn1[1] + ne.z*wn1[2]
                    + ne.w*wn1[3] + tv*wn1[4];
        float r_ = pv_sigm(Dr);
        float z_ = pv_sigm(Dz);
        float n_ = pv_tanh(gx1[2] + nterm + r_*(Dn + bh1));
        h1 = (1.0f - z_)*n_ + z_*h1;
        hseq[(t*128 + m0 + r_u)*261 + j1] = h1;
        A2[r_u*296 + j1] = pv_fp8_fast(4.0f*h1);
      }
      {
        float Dr = dsr[j2]*inv32 + gx2[0];
        float Dz = dsr[261 + j2]*inv32 + gx2[1];
        float Dn = dsr[522 + j2]*inv32;
        float nterm = ne.x*wn2[0] + ne.y*wn2[1] + ne.z*wn2[2]
                    + ne.w*wn2[3] + tv*wn2[4];
        float r_ = pv_sigm(Dr);
        float z_ = pv_sigm(Dz);
        float n_ = pv_tanh(gx2[2] + nterm + r_*(Dn + bh2));
        h2 = (1.0f - z_)*n_ + z_*h2;
        hseq[(t*128 + m0 + r_u)*261 + j2] = h2;
        A2[r_u*296 + j2] = pv_fp8_fast(4.0f*h2);
      }
      if (hasE3) {
        float Dr = dsr[j3]*inv32 + gx3[0];
        float Dz = dsr[261 + j3]*inv32 + gx3[1];
        float Dn = dsr[522 + j3]*inv32;
        float nterm = ne.x*wn3[0] + ne.y*wn3[1] + ne.z*wn3[2]
                    + ne.w*wn3[3] + tv*wn3[4];
        float r_ = pv_sigm(Dr);
        float z_ = pv_sigm(Dz);
        float n_ = pv_tanh(gx3[2] + nterm + r_*(Dn + bh3));
        h3 = (1.0f - z_)*n_ + z_*h3;
        hseq[(t*128 + m0 + r_u)*261 + j3] = h3;
        A2[r_u*296 + j3] = pv_fp8_fast(4.0f*h3);
      }
    }
    // noise/time cols for t+1
    if (t < 99 && tid >= 40 && tid < 60) {
      const int k = tid - 40;
      const int m = k/5, i = k - (k/5)*5;
      float v = (i < 4) ? noise[((t+1)*128 + m0 + m)*4 + i]*0.1f
                        : (t+1)*(1.0f/99.0f);
      A2[m*296 + 261 + i] = pv_fp8(4.0f*v);
    }
    __syncthreads();   // barrier B: A2 ready for next step
  }
}

// ---------------------------------------------------------------------------
// pv_frames: unchanged.
// ---------------------------------------------------------------------------
__global__ __launch_bounds__(256) void pv_frames(
    const float* hseq, const float* W1, const float* b1,
    const float* W2, const float* b2, float* out)
{
  __shared__ __align__(16) float h16[16*264];
  __shared__ unsigned w1p[64*133];
  __shared__ float f1s[16*66];
  __shared__ float w2s[576];
  const int tid = threadIdx.x;
  const int r0 = blockIdx.x * 16;    // rows rt = t*128 + b
  for (int i = tid; i < 16*264; i += 256) {
    int r = i / 264, k = i - r*264;
    h16[i] = (k < 261) ? hseq[(r0 + r)*261 + k] : 0.0f;
  }
  for (int i = tid; i < 64*131; i += 256) {
    int c = i/131, kp = i - (i/131)*131;
    int k = kp*2;
    float a0 = W1[c*261 + k];
    float a1 = (k + 1 < 261) ? W1[c*261 + k + 1] : 0.0f;
    w1p[c*133 + kp] = pv_pack2(a0, a1);
  }
  for (int i = tid; i < 576; i += 256) w2s[i] = W2[i];
  __syncthreads();
  #pragma unroll
  for (int e = 0; e < 4; ++e) {
    const int el = tid + e*256;
    const int r = el >> 6, c = el & 63;
    float s = b1[c];
    const unsigned* wp = w1p + c*133;
    const float* hr = h16 + r*264;
    for (int kp = 0; kp < 131; ++kp) {
      unsigned w = wp[kp];
      s += pv_lo(w)*hr[2*kp] + pv_hi(w)*hr[2*kp + 1];
    }
    f1s[r*66 + c] = fmaxf(s, 0.2f*s);
  }
  __syncthreads();
  if (tid < 144) {
    const int r = tid/9, oc = tid - (tid/9)*9;
    float s = b2[oc];
    const float* fr = f1s + r*66;
    const float* w = w2s + oc*64;
    #pragma unroll 8
    for (int k = 0; k < 64; ++k) s += fr[k]*w[k];
    const int rt = r0 + r;
    const int tt = rt >> 7, bb = rt & 127;
    out[bb*900 + tt*9 + oc] = pv_sigm(s);
  }
}

// ---------------------------------------------------------------------------
extern "C" __attribute__((visibility("default")))
void kernel_launch(void* const* d_in, const int* in_sizes, int n_in,
                   void* d_out, int out_size, void* d_ws, size_t ws_size,
                   hipStream_t stream)
{
  (void)in_sizes; (void)n_in; (void)out_size;
  const float* input_data = (const float*)d_in[0];
  const float* eps        = (const float*)d_in[1];
  const float* noise_eps  = (const float*)d_in[2];
  const float* proj_W     = (const float*)d_in[3];
  const float* proj_b     = (const float*)d_in[4];
  const float* lstm_Wih   = (const float*)d_in[5];
  const float* lstm_Whh   = (const float*)d_in[6];
  const float* lstm_bih   = (const float*)d_in[7];
  const float* lstm_bhh   = (const float*)d_in[8];
  const float* mu_W       = (const float*)d_in[9];
  const float* mu_b       = (const float*)d_in[10];
  const float* lv_W       = (const float*)d_in[11];
  const float* lv_b       = (const float*)d_in[12];
  const float* fcin_W     = (const float*)d_in[13];
  const float* fcin_b     = (const float*)d_in[14];
  const float* gru_Wih    = (const float*)d_in[15];
  const float* gru_Whh    = (const float*)d_in[16];
  const float* gru_bih    = (const float*)d_in[17];
  const float* gru_bhh    = (const float*)d_in[18];
  const float* jf_W1      = (const float*)d_in[19];
  const float* jf_b1      = (const float*)d_in[20];
  const float* jf_W2      = (const float*)d_in[21];
  const float* jf_b2      = (const float*)d_in[22];

  char* w = (char*)d_ws;
  float*              xg   = (float*)(w);                          // 26,214,400 B
  unsigned long long* wfp8 = (unsigned long long*)(w + 26214400);  //    235,008 B
  float*              hT   = (float*)(w + 26449408);               //     65,536 B
  float*              xvec = (float*)(w + 26514944);               //    131,072 B
  float*              gxb  = (float*)(w + 26646016);               //    400,896 B
  float*              hseq = (float*)(w + 27046912);               // 13,363,200 B (end 40,410,112)
  unsigned*           wihb = (unsigned*)(w + 40410112);            //  4,194,304 B (end 44,604,416)
  float*              outf = (float*)d_out;

  const int use_split = (ws_size >= (size_t)44604416ull);

  pv_prep_gru8<<<115, 256, 0, stream>>>(gru_Whh, gru_Wih, wfp8);
  if (use_split) {
    pv_prep_wih<<<1024, 256, 0, stream>>>(lstm_Wih, wihb);
    pv_gemm4<<<dim3(100, 2), 512, 0, stream>>>(input_data, proj_W, proj_b, wihb,
                                               lstm_bih, lstm_bhh, xg);
  } else {
    pv_gemm<<<dim3(100, 4), 256, 0, stream>>>(input_data, proj_W, proj_b,
                                              lstm_Wih, lstm_bih, lstm_bhh, xg);
  }
  pv_lstm3<<<32, 512, 0, stream>>>(xg, lstm_Whh, hT);
  pv_head<<<128, 64, 0, stream>>>(hT, eps, mu_W, mu_b, lv_W, lv_b,
                                  fcin_W, fcin_b, xvec, outf);
  pv_gxbase<<<dim3(16, 4), 256, 0, stream>>>(xvec, gru_Wih, gru_bih, gru_bhh, gxb);
  pv_gru5<<<32, 512, 0, stream>>>(gxb, wfp8, gru_Wih, gru_bhh, noise_eps, hseq);
  pv_frames<<<800, 256, 0, stream>>>(hseq, jf_W1, jf_b1, jf_W2, jf_b2, outf);
}

// Round 16
// 671.309 us; speedup vs baseline: 1.0735x; 1.0126x over previous
//
#include <hip/hip_runtime.h>
#include <hip/hip_bf16.h>

typedef float f32x4 __attribute__((ext_vector_type(4)));
typedef short s16x8 __attribute__((ext_vector_type(8)));

__device__ __forceinline__ float pv_sigm(float x){ return 1.0f/(1.0f + __expf(-x)); }
__device__ __forceinline__ float pv_tanh(float x){ float e = __expf(2.0f*x); return 1.0f - 2.0f/(e + 1.0f); }

__device__ __forceinline__ unsigned short pv_f2b(float x){
  union { float f; unsigned u; } c; c.f = x;
  unsigned r = (c.u + 0x7fffu + ((c.u >> 16) & 1u)) >> 16;
  return (unsigned short)r;
}
__device__ __forceinline__ unsigned pv_pack2(float a, float b){
  return ((unsigned)pv_f2b(b) << 16) | (unsigned)pv_f2b(a);
}
__device__ __forceinline__ float pv_lo(unsigned u){
  union { unsigned u; float f; } c; c.u = u << 16; return c.f;
}
__device__ __forceinline__ float pv_hi(unsigned u){
  union { unsigned u; float f; } c; c.u = u & 0xffff0000u; return c.f;
}

// manual OCP e4m3fn encode (RNE); valid for |x| < 448
__device__ __forceinline__ unsigned char pv_fp8(float x){
  union { float f; unsigned u; } c; c.f = x;
  unsigned s = (c.u >> 24) & 0x80u;
  unsigned au = c.u & 0x7fffffffu;
  if (au == 0u) return (unsigned char)s;
  int ex = (int)(au >> 23) - 127;
  if (ex < -6) ex = -6;
  union { unsigned u; float f; } iv; iv.u = (unsigned)(3 - ex + 127) << 23;
  union { unsigned u; float f; } a;  a.u = au;
  int q = (int)rintf(a.f * iv.f);
  if (q >= 16) { q >>= 1; ex += 1; }
  unsigned bits;
  if (ex == -6 && q < 8) bits = (unsigned)q;
  else bits = (unsigned)(((ex + 7) << 3) | (q - 8));
  return (unsigned char)(s | bits);
}

#if defined(__has_builtin)
#if __has_builtin(__builtin_amdgcn_cvt_pk_fp8_f32)
#define PV_HW_FP8 1
#endif
#endif
__device__ __forceinline__ unsigned char pv_fp8_fast(float x){
#ifdef PV_HW_FP8
  return (unsigned char)__builtin_amdgcn_cvt_pk_fp8_f32(x, x, 0, false);
#else
  return pv_fp8(x);
#endif
}

// ---------------------------------------------------------------------------
// pv_prep_gru8: unchanged (verified r4-r15).
// ---------------------------------------------------------------------------
__global__ void pv_prep_gru8(const float* Whh, const float* Wih,
                             unsigned long long* wfp8){
  int idx = blockIdx.x*256 + threadIdx.x;   // < 51*9*64 = 29376
  if (idx >= 29376) return;
  int T = idx / 576;
  int rem = idx - T*576;
  int c = rem >> 6;
  int l = rem & 63;
  int l16 = l & 15;
  int quad = l >> 4;
  int jb = T / 3;
  int ty = T - jb*3;
  int j = jb*16 + l16;
  int g = ty*261 + j;
  unsigned long long v = 0ull;
  #pragma unroll
  for (int e = 0; e < 8; ++e) {
    int k = c*32 + quad*8 + e;
    float w = 0.0f;
    if (j < 261) {
      if (k < 261) w = Whh[g*261 + k];
      else if (k < 266 && ty < 2) w = Wih[g*261 + 256 + (k - 261)];
    }
    v |= (unsigned long long)pv_fp8(8.0f*w) << (8*e);
  }
  wfp8[idx] = v;
}

// ---------------------------------------------------------------------------
// pv_prep_wih: unchanged.
// ---------------------------------------------------------------------------
__global__ __launch_bounds__(256) void pv_prep_wih(
    const float* __restrict__ Wih, unsigned* __restrict__ wihb)
{
  const int idx = blockIdx.x*256 + threadIdx.x;      // 262144 threads
  if (idx >= 262144) return;
  const float* src = Wih + idx*8;
  float4 a = *(const float4*)(src);
  float4 b = *(const float4*)(src + 4);
  uint4 o;
  o.x = pv_pack2(a.x, a.y);
  o.y = pv_pack2(a.z, a.w);
  o.z = pv_pack2(b.x, b.y);
  o.w = pv_pack2(b.z, b.w);
  *(uint4*)(wihb + idx*4) = o;
}

// ---------------------------------------------------------------------------
// pv_gemm5: r15 change = SINGLE-BARRIER pipeline.  gemm4's 2 barriers/step
// serialize the A-gen VALU phase against the MFMA/LDS phase for ALL waves
// (K-split null in r14 proved the bound is these shared per-CU pipes, not
// block-level TLP).  Here A-gen runs ONE STEP AHEAD (A-gen kk+1 while MFMA
// does kk) so the intra-step barrier disappears; Bs/Ws are 3-deep (staged
// 2 ahead).  Hazards (all disjoint, cross-wave slip <= 1 step bounded by
// the single barrier): ph2 writes As[(kk+1)&1] vs ph3 reads As[kk&1]
// (parity); ph4 writes Bs/Ws[(kk+2)%3] vs ph3 reads Bs[kk%3] / ph2 reads
// Ws[(kk+1)%3] (mod-3); every cross-step pair separated by >=1 barrier.
// Math / accumulation order bit-identical to gemm4.  LDS 85.8 KB.
// ---------------------------------------------------------------------------
__global__ __launch_bounds__(512, 1) void pv_gemm5(
    const float* __restrict__ pose, const float* __restrict__ projW,
    const float* __restrict__ projb, const unsigned* __restrict__ wihb,
    const float* __restrict__ bih, const float* __restrict__ bhh,
    float* __restrict__ xg)
{
  __shared__ __align__(16) unsigned As2[2][128*20];   // A bf16, 2-deep
  __shared__ __align__(16) unsigned Bs3[3][256*20];   // B bf16, 3-deep
  __shared__ __align__(16) float Ws3[3][320];         // W^T + bias, 3-deep

  const int tid = threadIdx.x;
  const int m0 = blockIdx.x * 128;
  const int n0 = blockIdx.y * 256;
  const int wave = tid >> 6, lane = tid & 63;
  const int wm = wave >> 2, wn = wave & 3;
  const int l16 = lane & 15, quad = lane >> 4;
  const int rl = tid >> 2, kq = tid & 3;       // A-gen: row rl, k-quarter kq
  const int rb = tid >> 1, hb = tid & 1;       // B-stage: row rb, half hb

  float p[9];
  {
    const float* pr = pose + (m0 + rl)*9;
    #pragma unroll
    for (int j = 0; j < 9; ++j) p[j] = pr[j];
  }

  // prologue: stage Ws/Bs for steps 0 and 1
  #pragma unroll
  for (int s = 0; s < 2; ++s) {
    if (tid < 320) {
      Ws3[s][tid < 288 ? ((tid >> 5)*32 + (tid & 31)) : tid] =
          (tid < 288) ? projW[s*288 + (tid & 31)*9 + (tid >> 5)]
                      : projb[s*32 + (tid - 288)];
    }
    const unsigned* src = wihb + (n0 + rb)*2048 + s*16 + hb*8;
    *(uint4*)(&Bs3[s][rb*20 + hb*8])     = *(const uint4*)(src);
    *(uint4*)(&Bs3[s][rb*20 + hb*8 + 4]) = *(const uint4*)(src + 4);
  }
  __syncthreads();
  // prologue A-gen for kk = 0 -> As2[0] (reads Ws3[0]); bit-identical math
  {
    const float* W = Ws3[0];
    f32x4 slo = *(const f32x4*)(W + 288 + kq*8);
    f32x4 shi = *(const f32x4*)(W + 292 + kq*8);
    #pragma unroll
    for (int j = 0; j < 9; ++j) {
      f32x4 wlo = *(const f32x4*)(W + j*32 + kq*8);
      f32x4 whi = *(const f32x4*)(W + j*32 + kq*8 + 4);
      slo += p[j]*wlo;
      shi += p[j]*whi;
    }
    #pragma unroll
    for (int e = 0; e < 4; ++e) {
      slo[e] = fmaxf(slo[e], 0.1f*slo[e]);
      shi[e] = fmaxf(shi[e], 0.1f*shi[e]);
    }
    uint4 av;
    av.x = pv_pack2(slo[0], slo[1]);
    av.y = pv_pack2(slo[2], slo[3]);
    av.z = pv_pack2(shi[0], shi[1]);
    av.w = pv_pack2(shi[2], shi[3]);
    *(uint4*)(&As2[0][rl*20 + kq*4]) = av;
  }
  __syncthreads();

  f32x4 acc[4][4];
  #pragma unroll
  for (int i = 0; i < 4; ++i)
    #pragma unroll
    for (int j = 0; j < 4; ++j) acc[i][j] = (f32x4){0.f,0.f,0.f,0.f};

  int b0 = 0, b1 = 1, b2 = 2;   // kk%3, (kk+1)%3, (kk+2)%3
  for (int kk = 0; kk < 128; ++kk) {
    const int k1 = kk + 1;
    const int k2 = kk + 2;

    // phase 1: issue global loads for kk+2 (land during this step's MFMA)
    uint4 bn0, bn1; float wv = 0.0f;
    if (k2 < 128) {
      const unsigned* bsrc = wihb + (n0 + rb)*2048 + k2*16 + hb*8;
      bn0 = *(const uint4*)(bsrc);
      bn1 = *(const uint4*)(bsrc + 4);
      if (tid < 320)
        wv = (tid < 288) ? projW[k2*288 + (tid & 31)*9 + (tid >> 5)]
                         : projb[k2*32 + (tid - 288)];
    }

    // phase 2: A-gen for kk+1 -> As2[k1&1] (reads Ws3[b1]); overlaps other
    // waves' MFMA phase (no barrier until end of step)
    if (k1 < 128) {
      const float* W = Ws3[b1];
      f32x4 slo = *(const f32x4*)(W + 288 + kq*8);
      f32x4 shi = *(const f32x4*)(W + 292 + kq*8);
      #pragma unroll
      for (int j = 0; j < 9; ++j) {
        f32x4 wlo = *(const f32x4*)(W + j*32 + kq*8);
        f32x4 whi = *(const f32x4*)(W + j*32 + kq*8 + 4);
        slo += p[j]*wlo;
        shi += p[j]*whi;
      }
      #pragma unroll
      for (int e = 0; e < 4; ++e) {
        slo[e] = fmaxf(slo[e], 0.1f*slo[e]);
        shi[e] = fmaxf(shi[e], 0.1f*shi[e]);
      }
      uint4 av;
      av.x = pv_pack2(slo[0], slo[1]);
      av.y = pv_pack2(slo[2], slo[3]);
      av.z = pv_pack2(shi[0], shi[1]);
      av.w = pv_pack2(shi[2], shi[3]);
      *(uint4*)(&As2[k1 & 1][rl*20 + kq*4]) = av;
    }

    // phase 3: MFMA for kk (reads As2[kk&1], Bs3[b0])
    {
      const unsigned short* As16 = (const unsigned short*)As2[kk & 1];
      const unsigned short* Bs16 = (const unsigned short*)Bs3[b0];
      s16x8 af[4];
      #pragma unroll
      for (int i = 0; i < 4; ++i)
        af[i] = *(const s16x8*)(As16 + (wm*64 + i*16 + l16)*40 + quad*8);
      #pragma unroll
      for (int j = 0; j < 4; ++j) {
        s16x8 bv = *(const s16x8*)(Bs16 + (wn*64 + j*16 + l16)*40 + quad*8);
        #pragma unroll
        for (int i = 0; i < 4; ++i)
          acc[i][j] = __builtin_amdgcn_mfma_f32_16x16x32_bf16(af[i], bv, acc[i][j], 0, 0, 0);
      }
    }

    // phase 4: write staged kk+2 -> Bs3[b2]/Ws3[b2]
    if (k2 < 128) {
      *(uint4*)(&Bs3[b2][rb*20 + hb*8])     = bn0;
      *(uint4*)(&Bs3[b2][rb*20 + hb*8 + 4]) = bn1;
      if (tid < 320)
        Ws3[b2][tid < 288 ? ((tid >> 5)*32 + (tid & 31)) : tid] = wv;
    }
    __syncthreads();   // single barrier: everything staged for kk+1 visible

    const int t = b0; b0 = b1; b1 = b2; b2 = t;   // rotate mod-3 indices
  }

  #pragma unroll
  for (int j = 0; j < 4; ++j) {
    int col = n0 + wn*64 + j*16 + l16;
    float bsum = bih[col] + bhh[col];
    #pragma unroll
    for (int i = 0; i < 4; ++i) {
      #pragma unroll
      for (int r = 0; r < 4; ++r) {
        int row = m0 + wm*64 + i*16 + quad*4 + r;
        int bb = row / 100;
        int tt = row - bb*100;
        xg[(tt*128 + bb)*512 + col] = acc[i][j][r] + bsum;
      }
    }
  }
}

// ---------------------------------------------------------------------------
// pv_gemm: old fused path (fallback). Unchanged.
// ---------------------------------------------------------------------------
__global__ __launch_bounds__(256) void pv_gemm(
    const float* pose, const float* projW, const float* projb,
    const float* Wih, const float* bih, const float* bhh,
    float* xg)
{
  __shared__ __align__(16) unsigned As[128*24];
  __shared__ __align__(16) unsigned Bs[128*24];
  __shared__ float Ws[320];

  const int tid = threadIdx.x;
  const int m0 = blockIdx.x * 128;
  const int n0 = blockIdx.y * 128;

  const int rl = tid >> 1;
  const int kh = tid & 1;
  float p0,p1,p2,p3,p4,p5,p6,p7,p8;
  {
    const float* pr = pose + (m0 + rl) * 9;
    p0=pr[0]; p1=pr[1]; p2=pr[2]; p3=pr[3]; p4=pr[4];
    p5=pr[5]; p6=pr[6]; p7=pr[7]; p8=pr[8];
  }

  const int wave = tid >> 6;
  const int lane = tid & 63;
  const int wm = wave >> 1, wn = wave & 1;
  const int l16 = lane & 15, quad = lane >> 4;

  f32x4 acc[4][4];
  #pragma unroll
  for (int i = 0; i < 4; ++i)
    #pragma unroll
    for (int j = 0; j < 4; ++j) acc[i][j] = (f32x4){0.f,0.f,0.f,0.f};

  for (int kk = 0; kk < 128; ++kk) {
    __syncthreads();
    for (int idx = tid; idx < 320; idx += 256)
      Ws[idx] = (idx < 288) ? projW[kk*288 + idx] : projb[kk*32 + (idx - 288)];
    #pragma unroll
    for (int i = 0; i < 8; ++i) {
      int q = tid + i*256;
      int nl = q >> 4;
      int kp = q & 15;
      const float* src = Wih + (n0 + nl)*4096 + kk*32 + kp*2;
      Bs[nl*24 + kp] = pv_pack2(src[0], src[1]);
    }
    __syncthreads();
    {
      const int kbase = kh*16;
      const float* wbase = Ws + kbase*9;
      float av[16];
      #pragma unroll
      for (int u = 0; u < 16; ++u) {
        const float* wr = wbase + u*9;
        float s = Ws[288 + kbase + u]
                + p0*wr[0] + p1*wr[1] + p2*wr[2] + p3*wr[3] + p4*wr[4]
                + p5*wr[5] + p6*wr[6] + p7*wr[7] + p8*wr[8];
        av[u] = fmaxf(s, 0.1f*s);
      }
      #pragma unroll
      for (int q = 0; q < 8; ++q)
        As[rl*24 + kh*8 + q] = pv_pack2(av[2*q], av[2*q+1]);
    }
    __syncthreads();
    const unsigned short* As16 = (const unsigned short*)As;
    const unsigned short* Bs16 = (const unsigned short*)Bs;
    s16x8 af[4], bfv[4];
    #pragma unroll
    for (int i = 0; i < 4; ++i)
      af[i] = *(const s16x8*)(As16 + (wm*64 + i*16 + l16)*48 + quad*8);
    #pragma unroll
    for (int j = 0; j < 4; ++j)
      bfv[j] = *(const s16x8*)(Bs16 + (wn*64 + j*16 + l16)*48 + quad*8);
    #pragma unroll
    for (int i = 0; i < 4; ++i)
      #pragma unroll
      for (int j = 0; j < 4; ++j)
        acc[i][j] = __builtin_amdgcn_mfma_f32_16x16x32_bf16(af[i], bfv[j], acc[i][j], 0, 0, 0);
  }
  #pragma unroll
  for (int j = 0; j < 4; ++j) {
    int col = n0 + wn*64 + j*16 + l16;
    float bsum = bih[col] + bhh[col];
    #pragma unroll
    for (int i = 0; i < 4; ++i) {
      #pragma unroll
      for (int r = 0; r < 4; ++r) {
        int row = m0 + wm*64 + i*16 + quad*4 + r;
        int bb = row / 100;
        int tt = row - bb*100;
        xg[(tt*128 + bb)*512 + col] = acc[i][j][r] + bsum;
      }
    }
  }
}

// ---------------------------------------------------------------------------
// pv_lstm3: unchanged from round 13 (passed).
// ---------------------------------------------------------------------------
__global__ __launch_bounds__(512, 1) void pv_lstm3(
    const float* __restrict__ xg, const float* __restrict__ Whh,
    float* __restrict__ hT)
{
  __shared__ __align__(16) unsigned short Hs[16*136];  // [b16][u128+pad], rows 4+ = 0
  __shared__ __align__(16) float Ds[4*512];            // [b4][gate512]
  const int tid = threadIdx.x;
  const int wv = tid >> 6;           // 0..7
  const int lane = tid & 63;
  const int l16 = lane & 15, quad = lane >> 4;
  const int m0 = blockIdx.x * 4;
  const int j = wv*16 + l16;         // unit for MFMA B-frag

  s16x8 bfr[4][4];
  #pragma unroll
  for (int ty = 0; ty < 4; ++ty) {
    const int g = ty*128 + j;
    #pragma unroll
    for (int c = 0; c < 4; ++c) {
      s16x8 v;
      #pragma unroll
      for (int e = 0; e < 8; ++e)
        v[e] = (short)pv_f2b(Whh[g*128 + c*32 + quad*8 + e]);
      bfr[ty][c] = v;
    }
  }
  for (int i = tid; i < 16*136; i += 512) Hs[i] = 0;

  const int r_u = tid >> 7;          // 0..3
  const int j_u = tid & 127;         // 0..127
  float cst = 0.0f;
  const float* xbase = xg + (m0 + r_u)*512 + j_u;

  float xv[4];
  #pragma unroll
  for (int ty = 0; ty < 4; ++ty) xv[ty] = xbase[ty*128];
  __syncthreads();

  for (int t = 0; t < 100; ++t) {
    float xn[4];
    if (t < 99) {
      #pragma unroll
      for (int ty = 0; ty < 4; ++ty)
        xn[ty] = xbase[(t+1)*65536 + ty*128];
    }
    f32x4 acc[4];
    #pragma unroll
    for (int ty = 0; ty < 4; ++ty) acc[ty] = (f32x4){0.f,0.f,0.f,0.f};
    #pragma unroll
    for (int c = 0; c < 4; ++c) {
      s16x8 a = *(const s16x8*)(&Hs[l16*136 + c*32 + quad*8]);
      #pragma unroll
      for (int ty = 0; ty < 4; ++ty)
        acc[ty] = __builtin_amdgcn_mfma_f32_16x16x32_bf16(a, bfr[ty][c], acc[ty], 0, 0, 0);
    }
    if (quad == 0) {
      #pragma unroll
      for (int ty = 0; ty < 4; ++ty)
        #pragma unroll
        for (int r = 0; r < 4; ++r)
          Ds[r*512 + ty*128 + j] = acc[ty][r];
    }
    __syncthreads();   // barrier A: Ds ready, Hs reads done

    {
      const float* dsr = Ds + r_u*512;
      float gi = dsr[j_u]       + xv[0];
      float gf = dsr[128 + j_u] + xv[1];
      float gg = dsr[256 + j_u] + xv[2];
      float go = dsr[384 + j_u] + xv[3];
      float c_ = pv_sigm(gf)*cst + pv_sigm(gi)*pv_tanh(gg);
      cst = c_;
      float h = pv_sigm(go)*pv_tanh(c_);
      Hs[r_u*136 + j_u] = pv_f2b(h);
      if (t == 99) hT[(m0 + r_u)*128 + j_u] = h;
    }
    if (t < 99) {
      #pragma unroll
      for (int ty = 0; ty < 4; ++ty) xv[ty] = xn[ty];
    }
    __syncthreads();   // barrier B: Hs ready for next step
  }
}

// ---------------------------------------------------------------------------
// pv_head: unchanged.
// ---------------------------------------------------------------------------
__global__ __launch_bounds__(64) void pv_head(
    const float* hT, const float* eps,
    const float* muW, const float* mub,
    const float* lvW, const float* lvb,
    const float* fcW, const float* fcb,
    float* xvec, float* out)
{
  __shared__ float hrow[128];
  __shared__ float emb[64];
  const int b = blockIdx.x, j = threadIdx.x;
  hrow[j] = hT[b*128 + j];
  hrow[j + 64] = hT[b*128 + 64 + j];
  __syncthreads();
  float sm = mub[j], sl = lvb[j];
  for (int k = 0; k < 128; ++k) {
    sm += hrow[k]*muW[j*128 + k];
    sl += hrow[k]*lvW[j*128 + k];
  }
  float mu = fmaxf(sm, 0.1f*sm);
  float lv = fmaxf(sl, 0.1f*sl);
  lv = fminf(fmaxf(lv, -10.0f), 10.0f);
  float em = mu + eps[b*64 + j]*__expf(0.5f*lv);
  emb[j] = em;
  out[115200 + b*64 + j] = mu;
  out[123392 + b*64 + j] = lv;
  __syncthreads();
  for (int c4 = 0; c4 < 4; ++c4) {
    int c = c4*64 + j;
    float s = fcb[c];
    for (int k = 0; k < 64; ++k) s += emb[k]*fcW[c*64 + k];
    xvec[b*256 + c] = s;
  }
}

// ---------------------------------------------------------------------------
// pv_gxbase: unchanged.
// ---------------------------------------------------------------------------
__global__ __launch_bounds__(256) void pv_gxbase(
    const float* xvec, const float* Wih,
    const float* bih, const float* bhh, float* gxb)
{
  __shared__ float xs[8*256];
  const int tid = threadIdx.x;
  const int bg = blockIdx.x;
  const int gg = blockIdx.y;
  for (int i = tid; i < 2048; i += 256) xs[i] = xvec[bg*2048 + i];
  __syncthreads();
  const int g = gg*256 + tid;
  if (g >= 783) return;
  float bias = bih[g] + ((g < 522) ? bhh[g] : 0.0f);
  float a0=bias,a1=bias,a2=bias,a3=bias,a4=bias,a5=bias,a6=bias,a7=bias;
  const float* wr = Wih + g*261;
  for (int k = 0; k < 256; ++k) {
    float w = wr[k];
    a0 += xs[0*256 + k]*w; a1 += xs[1*256 + k]*w;
    a2 += xs[2*256 + k]*w; a3 += xs[3*256 + k]*w;
    a4 += xs[4*256 + k]*w; a5 += xs[5*256 + k]*w;
    a6 += xs[6*256 + k]*w; a7 += xs[7*256 + k]*w;
  }
  gxb[(bg*8 + 0)*783 + g] = a0; gxb[(bg*8 + 1)*783 + g] = a1;
  gxb[(bg*8 + 2)*783 + g] = a2; gxb[(bg*8 + 3)*783 + g] = a3;
  gxb[(bg*8 + 4)*783 + g] = a4; gxb[(bg*8 + 5)*783 + g] = a5;
  gxb[(bg*8 + 6)*783 + g] = a6; gxb[(bg*8 + 7)*783 + g] = a7;
}

// ---------------------------------------------------------------------------
// pv_gru5: byte-identical to the round-10/12/13/15 version (252-261us).
// ---------------------------------------------------------------------------
__global__ __launch_bounds__(512, 1) void pv_gru5(
    const float* __restrict__ gxb, const unsigned long long* __restrict__ wfp8,
    const float* __restrict__ Wih, const float* __restrict__ bhh,
    const float* __restrict__ noise, float* __restrict__ hseq)
{
  __shared__ __align__(16) unsigned long long Bl[27*9*64];   // 124,416 B
  __shared__ __align__(16) unsigned char A2[16*296];         //   4,736 B
  __shared__ __align__(16) float Ds[4*792];                  //  12,672 B
  const int tid = threadIdx.x;
  const int wv = tid >> 6;           // 0..7
  const int lane = tid & 63;
  const int l16 = lane & 15, quad = lane >> 4;
  const int m0 = blockIdx.x * 4;
  const int tailOwner = (wv >= 5);   // waves 5/6/7 own tail tiles 48/49/50

  // register B: tiles 3wv..3wv+2 (jb = wv, ty = 0..2)
  long bfr[3][9];
  #pragma unroll
  for (int s = 0; s < 3; ++s)
    #pragma unroll
    for (int c = 0; c < 9; ++c)
      bfr[s][c] = (long)wfp8[((3*wv + s)*9 + c)*64 + lane];
  #pragma unroll
  for (int s = 0; s < 3; ++s)
    #pragma unroll
    for (int c = 0; c < 9; ++c)
      asm volatile("" : "+v"(bfr[s][c]));

  // ---- per-thread update elements: (j1, r), (j2 = j1+128, r), tid<20: (j3, r)
  const int r_u = tid & 3;
  const int j1 = tid >> 2;           // 0..127
  const int j2 = 128 + j1;           // 128..255
  const int hasE3 = (tid < 20);
  const int j3 = 256 + (tid >> 2);   // 256..260 (valid when tid<20)
  float gx1[3], gx2[3], gx3[3], wn1[5], wn2[5], wn3[5];
  float bh1, bh2, bh3 = 0.f, h1 = 0.f, h2 = 0.f, h3 = 0.f;
  {
    const float* gb = gxb + (m0 + r_u)*783;
    gx1[0] = gb[j1]; gx1[1] = gb[261 + j1]; gx1[2] = gb[522 + j1];
    gx2[0] = gb[j2]; gx2[1] = gb[261 + j2]; gx2[2] = gb[522 + j2];
    const float* w1 = Wih + (522 + j1)*261 + 256;
    wn1[0] = 0.1f*w1[0]; wn1[1] = 0.1f*w1[1]; wn1[2] = 0.1f*w1[2];
    wn1[3] = 0.1f*w1[3]; wn1[4] = w1[4];
    const float* w2 = Wih + (522 + j2)*261 + 256;
    wn2[0] = 0.1f*w2[0]; wn2[1] = 0.1f*w2[1]; wn2[2] = 0.1f*w2[2];
    wn2[3] = 0.1f*w2[3]; wn2[4] = w2[4];
    bh1 = bhh[522 + j1];
    bh2 = bhh[522 + j2];
    #pragma unroll
    for (int k = 0; k < 3; ++k) gx3[k] = 0.f;
    #pragma unroll
    for (int k = 0; k < 5; ++k) wn3[k] = 0.f;
    if (hasE3) {
      gx3[0] = gb[j3]; gx3[1] = gb[261 + j3]; gx3[2] = gb[522 + j3];
      const float* w3 = Wih + (522 + j3)*261 + 256;
      wn3[0] = 0.1f*w3[0]; wn3[1] = 0.1f*w3[1]; wn3[2] = 0.1f*w3[2];
      wn3[3] = 0.1f*w3[3]; wn3[4] = w3[4];
      bh3 = bhh[522 + j3];
    }
  }

  // ---- stage LDS ----
  for (int i = tid; i < 27*9*64; i += 512) Bl[i] = wfp8[24*9*64 + i];
  for (int i = tid; i < 4736; i += 512) A2[i] = 0;
  __syncthreads();
  if (tid < 20) {   // t=0 noise/time cols (time_0 = 0)
    const int m = tid/5, i = tid - (tid/5)*5;
    float v = (i < 4) ? noise[(m0 + m)*4 + i]*0.1f : 0.0f;
    A2[m*296 + 261 + i] = pv_fp8(4.0f*v);
  }
  __syncthreads();

  const float inv32 = 1.0f/32.0f;
  const float* nptr = noise + (m0 + r_u)*4;
  for (int t = 0; t < 100; ++t) {
    // issue noise load early (independent of this step's compute)
    const float4 ne = *(const float4*)(nptr + t*512);

    f32x4 acc[7];
    #pragma unroll
    for (int s = 0; s < 7; ++s) acc[s] = (f32x4){0,0,0,0};
    #pragma unroll
    for (int c = 0; c < 9; ++c) {
      const long a = *(const long*)(&A2[l16*296 + c*32 + quad*8]);
      acc[0] = __builtin_amdgcn_mfma_f32_16x16x32_fp8_fp8(a, bfr[0][c], acc[0], 0, 0, 0);
      acc[1] = __builtin_amdgcn_mfma_f32_16x16x32_fp8_fp8(a, bfr[1][c], acc[1], 0, 0, 0);
      acc[2] = __builtin_amdgcn_mfma_f32_16x16x32_fp8_fp8(a, bfr[2][c], acc[2], 0, 0, 0);
      const long b3 = (long)Bl[((3*wv + 0)*9 + c)*64 + lane];
      const long b4 = (long)Bl[((3*wv + 1)*9 + c)*64 + lane];
      const long b5 = (long)Bl[((3*wv + 2)*9 + c)*64 + lane];
      acc[3] = __builtin_amdgcn_mfma_f32_16x16x32_fp8_fp8(a, b3, acc[3], 0, 0, 0);
      acc[4] = __builtin_amdgcn_mfma_f32_16x16x32_fp8_fp8(a, b4, acc[4], 0, 0, 0);
      acc[5] = __builtin_amdgcn_mfma_f32_16x16x32_fp8_fp8(a, b5, acc[5], 0, 0, 0);
      if (tailOwner) {
        const long b6 = (long)Bl[((24 + (wv - 5))*9 + c)*64 + lane];
        acc[6] = __builtin_amdgcn_mfma_f32_16x16x32_fp8_fp8(a, b6, acc[6], 0, 0, 0);
      }
    }
    // gate export: all owned tiles -> Ds[r][g]
    if (quad == 0) {
      #pragma unroll
      for (int s = 0; s < 3; ++s) {
        const int g = s*261 + wv*16 + l16;
        #pragma unroll
        for (int r = 0; r < 4; ++r) Ds[r*792 + g] = acc[s][r];
      }
      #pragma unroll
      for (int s = 0; s < 3; ++s) {
        const int g = s*261 + (8 + wv)*16 + l16;
        #pragma unroll
        for (int r = 0; r < 4; ++r) Ds[r*792 + g] = acc[3 + s][r];
      }
      if (tailOwner && l16 < 5) {
        const int g = (wv - 5)*261 + 256 + l16;
        #pragma unroll
        for (int r = 0; r < 4; ++r) Ds[r*792 + g] = acc[6][r];
      }
    }
    __syncthreads();   // barrier A: Ds complete, A2 reads done

    // ---- distributed update: elements (j1,r_u), (j2,r_u), [tid<20: (j3,r_u)]
    {
      const float tv = (float)t * (1.0f/99.0f);
      const float* dsr = Ds + r_u*792;
      {
        float Dr = dsr[j1]*inv32 + gx1[0];
        float Dz = dsr[261 + j1]*inv32 + gx1[1];
        float Dn = dsr[522 + j1]*inv32;
        float nterm = ne.x*wn1[0] + ne.y*wn1[1] + ne.z*wn1[2]
                    + ne.w*wn1[3] + tv*wn1[4];
        float r_ = pv_sigm(Dr);
        float z_ = pv_sigm(Dz);
        float n_ = pv_tanh(gx1[2] + nterm + r_*(Dn + bh1));
        h1 = (1.0f - z_)*n_ + z_*h1;
        hseq[(t*128 + m0 + r_u)*261 + j1] = h1;
        A2[r_u*296 + j1] = pv_fp8_fast(4.0f*h1);
      }
      {
        float Dr = dsr[j2]*inv32 + gx2[0];
        float Dz = dsr[261 + j2]*inv32 + gx2[1];
        float Dn = dsr[522 + j2]*inv32;
        float nterm = ne.x*wn2[0] + ne.y*wn2[1] + ne.z*wn2[2]
                    + ne.w*wn2[3] + tv*wn2[4];
        float r_ = pv_sigm(Dr);
        float z_ = pv_sigm(Dz);
        float n_ = pv_tanh(gx2[2] + nterm + r_*(Dn + bh2));
        h2 = (1.0f - z_)*n_ + z_*h2;
        hseq[(t*128 + m0 + r_u)*261 + j2] = h2;
        A2[r_u*296 + j2] = pv_fp8_fast(4.0f*h2);
      }
      if (hasE3) {
        float Dr = dsr[j3]*inv32 + gx3[0];
        float Dz = dsr[261 + j3]*inv32 + gx3[1];
        float Dn = dsr[522 + j3]*inv32;
        float nterm = ne.x*wn3[0] + ne.y*wn3[1] + ne.z*wn3[2]
                    + ne.w*wn3[3] + tv*wn3[4];
        float r_ = pv_sigm(Dr);
        float z_ = pv_sigm(Dz);
        float n_ = pv_tanh(gx3[2] + nterm + r_*(Dn + bh3));
        h3 = (1.0f - z_)*n_ + z_*h3;
        hseq[(t*128 + m0 + r_u)*261 + j3] = h3;
        A2[r_u*296 + j3] = pv_fp8_fast(4.0f*h3);
      }
    }
    // noise/time cols for t+1
    if (t < 99 && tid >= 40 && tid < 60) {
      const int k = tid - 40;
      const int m = k/5, i = k - (k/5)*5;
      float v = (i < 4) ? noise[((t+1)*128 + m0 + m)*4 + i]*0.1f
                        : (t+1)*(1.0f/99.0f);
      A2[m*296 + 261 + i] = pv_fp8(4.0f*v);
    }
    __syncthreads();   // barrier B: A2 ready for next step
  }
}

// ---------------------------------------------------------------------------
// pv_frames: unchanged.
// ---------------------------------------------------------------------------
__global__ __launch_bounds__(256) void pv_frames(
    const float* hseq, const float* W1, const float* b1,
    const float* W2, const float* b2, float* out)
{
  __shared__ __align__(16) float h16[16*264];
  __shared__ unsigned w1p[64*133];
  __shared__ float f1s[16*66];
  __shared__ float w2s[576];
  const int tid = threadIdx.x;
  const int r0 = blockIdx.x * 16;    // rows rt = t*128 + b
  for (int i = tid; i < 16*264; i += 256) {
    int r = i / 264, k = i - r*264;
    h16[i] = (k < 261) ? hseq[(r0 + r)*261 + k] : 0.0f;
  }
  for (int i = tid; i < 64*131; i += 256) {
    int c = i/131, kp = i - (i/131)*131;
    int k = kp*2;
    float a0 = W1[c*261 + k];
    float a1 = (k + 1 < 261) ? W1[c*261 + k + 1] : 0.0f;
    w1p[c*133 + kp] = pv_pack2(a0, a1);
  }
  for (int i = tid; i < 576; i += 256) w2s[i] = W2[i];
  __syncthreads();
  #pragma unroll
  for (int e = 0; e < 4; ++e) {
    const int el = tid + e*256;
    const int r = el >> 6, c = el & 63;
    float s = b1[c];
    const unsigned* wp = w1p + c*133;
    const float* hr = h16 + r*264;
    for (int kp = 0; kp < 131; ++kp) {
      unsigned w = wp[kp];
      s += pv_lo(w)*hr[2*kp] + pv_hi(w)*hr[2*kp + 1];
    }
    f1s[r*66 + c] = fmaxf(s, 0.2f*s);
  }
  __syncthreads();
  if (tid < 144) {
    const int r = tid/9, oc = tid - (tid/9)*9;
    float s = b2[oc];
    const float* fr = f1s + r*66;
    const float* w = w2s + oc*64;
    #pragma unroll 8
    for (int k = 0; k < 64; ++k) s += fr[k]*w[k];
    const int rt = r0 + r;
    const int tt = rt >> 7, bb = rt & 127;
    out[bb*900 + tt*9 + oc] = pv_sigm(s);
  }
}

// ---------------------------------------------------------------------------
extern "C" __attribute__((visibility("default")))
void kernel_launch(void* const* d_in, const int* in_sizes, int n_in,
                   void* d_out, int out_size, void* d_ws, size_t ws_size,
                   hipStream_t stream)
{
  (void)in_sizes; (void)n_in; (void)out_size;
  const float* input_data = (const float*)d_in[0];
  const float* eps        = (const float*)d_in[1];
  const float* noise_eps  = (const float*)d_in[2];
  const float* proj_W     = (const float*)d_in[3];
  const float* proj_b     = (const float*)d_in[4];
  const float* lstm_Wih   = (const float*)d_in[5];
  const float* lstm_Whh   = (const float*)d_in[6];
  const float* lstm_bih   = (const float*)d_in[7];
  const float* lstm_bhh   = (const float*)d_in[8];
  const float* mu_W       = (const float*)d_in[9];
  const float* mu_b       = (const float*)d_in[10];
  const float* lv_W       = (const float*)d_in[11];
  const float* lv_b       = (const float*)d_in[12];
  const float* fcin_W     = (const float*)d_in[13];
  const float* fcin_b     = (const float*)d_in[14];
  const float* gru_Wih    = (const float*)d_in[15];
  const float* gru_Whh    = (const float*)d_in[16];
  const float* gru_bih    = (const float*)d_in[17];
  const float* gru_bhh    = (const float*)d_in[18];
  const float* jf_W1      = (const float*)d_in[19];
  const float* jf_b1      = (const float*)d_in[20];
  const float* jf_W2      = (const float*)d_in[21];
  const float* jf_b2      = (const float*)d_in[22];

  char* w = (char*)d_ws;
  float*              xg   = (float*)(w);                          // 26,214,400 B
  unsigned long long* wfp8 = (unsigned long long*)(w + 26214400);  //    235,008 B
  float*              hT   = (float*)(w + 26449408);               //     65,536 B
  float*              xvec = (float*)(w + 26514944);               //    131,072 B
  float*              gxb  = (float*)(w + 26646016);               //    400,896 B
  float*              hseq = (float*)(w + 27046912);               // 13,363,200 B (end 40,410,112)
  unsigned*           wihb = (unsigned*)(w + 40410112);            //  4,194,304 B (end 44,604,416)
  float*              outf = (float*)d_out;

  const int use_split = (ws_size >= (size_t)44604416ull);

  pv_prep_gru8<<<115, 256, 0, stream>>>(gru_Whh, gru_Wih, wfp8);
  if (use_split) {
    pv_prep_wih<<<1024, 256, 0, stream>>>(lstm_Wih, wihb);
    pv_gemm5<<<dim3(100, 2), 512, 0, stream>>>(input_data, proj_W, proj_b, wihb,
                                               lstm_bih, lstm_bhh, xg);
  } else {
    pv_gemm<<<dim3(100, 4), 256, 0, stream>>>(input_data, proj_W, proj_b,
                                              lstm_Wih, lstm_bih, lstm_bhh, xg);
  }
  pv_lstm3<<<32, 512, 0, stream>>>(xg, lstm_Whh, hT);
  pv_head<<<128, 64, 0, stream>>>(hT, eps, mu_W, mu_b, lv_W, lv_b,
                                  fcin_W, fcin_b, xvec, outf);
  pv_gxbase<<<dim3(16, 4), 256, 0, stream>>>(xvec, gru_Wih, gru_bih, gru_bhh, gxb);
  pv_gru5<<<32, 512, 0, stream>>>(gxb, wfp8, gru_Wih, gru_bhh, noise_eps, hseq);
  pv_frames<<<800, 256, 0, stream>>>(hseq, jf_W1, jf_b1, jf_W2, jf_b2, outf);
}